// Round 12
// baseline (239.149 us; speedup 1.0000x reference)
//
#include <hip/hip_runtime.h>
#include <hip/hip_bf16.h>

typedef unsigned short u16;
typedef unsigned long long u64;
typedef __attribute__((ext_vector_type(8))) short bf8;   // 8 bf16 (raw bits, 4 VGPRs)
typedef __attribute__((ext_vector_type(4))) short bf4;   // 4 bf16 (2 VGPRs)
typedef __attribute__((ext_vector_type(4))) float f32x4;

#define CH_ 512
#define NSP 1024      // 32*32 spatial
#define NB 8
#define CONDDIM 1280
#define NGROUP 64     // 512/8
#define HEADS_ 8
#define HD 64         // head dim
#define PR 34         // padded row length (32 + 2)
#define PPB (PR*PR)   // padded positions per batch = 1156
#define QSCALE 0.18033688011112042f   // 0.125 * log2(e): softmax in exp2 domain

#define VWAIT(N) asm volatile("s_waitcnt vmcnt(" #N ")" ::: "memory")
#define SCHEDB __builtin_amdgcn_sched_barrier(0)
#define BARRIER do { SCHEDB; __builtin_amdgcn_s_barrier(); SCHEDB; } while (0)

__device__ __forceinline__ u16 f2bf(float f) {
  union { float f; unsigned u; } v; v.f = f;
  unsigned u = v.u;
  return (u16)((u + 0x7fffu + ((u >> 16) & 1u)) >> 16);   // RNE
}

__device__ __forceinline__ unsigned cvt_pk_bf16(float lo, float hi) {
  unsigned r;
  asm volatile("v_cvt_pk_bf16_f32 %0, %1, %2" : "=v"(r) : "v"(lo), "v"(hi));
  return r;
}

__device__ __forceinline__ f32x4 mfma_bf16(bf8 a, bf8 b, f32x4 c) {
  return __builtin_amdgcn_mfma_f32_16x16x32_bf16(a, b, c, 0, 0, 0);
}

__device__ __forceinline__ void gload16(const void* g, void* l) {
  __builtin_amdgcn_global_load_lds((const __attribute__((address_space(1))) void*)g,
                                   (__attribute__((address_space(3))) void*)l, 16, 0, 0);
}

// ---------------- pack / transpose kernels ----------------

// x: NCHW f32 -> xp: padded NHWC bf16 [B][34][34][512] (interior only)
__global__ __launch_bounds__(1024) void pack_x_kernel(const float* __restrict__ x, u16* __restrict__ xp) {
  __shared__ float t[32][33];
  int b = blockIdx.z;
  int c0 = blockIdx.y * 32, p0 = blockIdx.x * 32;
  int tx = threadIdx.x & 31, ty = threadIdx.x >> 5;
  t[ty][tx] = x[((size_t)b * CH_ + c0 + ty) * NSP + p0 + tx];
  __syncthreads();
  int p = p0 + ty;
  int y = p >> 5, xc = p & 31;
  xp[((size_t)b * PPB + (size_t)(y + 1) * PR + xc + 1) * CH_ + c0 + tx] = f2bf(t[tx][ty]);
}

// zero the borders of two padded bf16 buffers
__global__ __launch_bounds__(256) void border_zero_kernel(u16* __restrict__ a, u16* __restrict__ b) {
  int id = blockIdx.x * 256 + threadIdx.x;   // (b, border-pos, ch-chunk of 8)
  if (id >= NB * 132 * 64) return;
  int ch8 = id & 63;
  int rest = id >> 6;
  int bidx = rest % 132;
  int bb = rest / 132;
  int r, c;
  if (bidx < 34)       { r = 0;          c = bidx; }
  else if (bidx < 68)  { r = 33;         c = bidx - 34; }
  else if (bidx < 100) { r = bidx - 67;  c = 0; }
  else                 { r = bidx - 99;  c = 33; }
  size_t off = ((size_t)bb * PPB + (size_t)r * PR + c) * CH_ + ch8 * 8;
  const bf8 z = {0, 0, 0, 0, 0, 0, 0, 0};
  *(bf8*)(a + off) = z;
  *(bf8*)(b + off) = z;
}

// BOTH 3x3 weights in one launch (blockIdx.y selects tensor)
__global__ __launch_bounds__(256) void pack_w3_kernel(const float* __restrict__ wA, const float* __restrict__ wB,
                                                      u16* __restrict__ dA, u16* __restrict__ dB) {
  int id = blockIdx.x * 256 + threadIdx.x;        // (t, cib, co)
  if (id >= 9 * 64 * CH_) return;
  const float* w = blockIdx.y ? wB : wA;
  u16* wp = blockIdx.y ? dB : dA;
  int co = id & (CH_ - 1);
  int cib = (id >> 9) & 63;
  int t = id >> 15;
  int dy = t / 3, dx = t % 3;
  bf8 v;
#pragma unroll
  for (int j = 0; j < 8; j++) {
    int ci = cib * 8 + j;
    v[j] = (short)f2bf(w[(((size_t)co * CH_ + ci) * 3 + dy) * 3 + dx]);
  }
  *(bf8*)(wp + ((size_t)(t * 64 + cib) * CH_ + co) * 8) = v;
}

// ALL five 1x1 weights in one launch (blockIdx.y selects tensor)
__global__ __launch_bounds__(256) void pack_w1_kernel(
    const float* __restrict__ s0, const float* __restrict__ s1, const float* __restrict__ s2,
    const float* __restrict__ s3, const float* __restrict__ s4,
    u16* __restrict__ d0, u16* __restrict__ d1, u16* __restrict__ d2,
    u16* __restrict__ d3, u16* __restrict__ d4) {
  int id = blockIdx.x * 256 + threadIdx.x;        // (cib, co)
  if (id >= 64 * CH_) return;
  const float* w; u16* wp;
  switch (blockIdx.y) {
    case 0: w = s0; wp = d0; break;
    case 1: w = s1; wp = d1; break;
    case 2: w = s2; wp = d2; break;
    case 3: w = s3; wp = d3; break;
    default: w = s4; wp = d4; break;
  }
  int co = id & (CH_ - 1);
  int cib = id >> 9;
  bf8 v;
#pragma unroll
  for (int j = 0; j < 8; j++) v[j] = (short)f2bf(w[(size_t)co * CH_ + cib * 8 + j]);
  *(bf8*)(wp + ((size_t)cib * CH_ + co) * 8) = v;
}

// cond[b][c] = conditioning[b] . cpw[c] + cpb[c]   (f32)
__global__ __launch_bounds__(256) void cond_kernel(const float* __restrict__ cd, const float* __restrict__ cpw,
                                                   const float* __restrict__ cpb, float* __restrict__ cond) {
  int b = blockIdx.y;
  int c = blockIdx.x * 4 + (threadIdx.x >> 6);
  int lane = threadIdx.x & 63;
  const float* wrow = cpw + (size_t)c * CONDDIM;
  const float* crow = cd + (size_t)b * CONDDIM;
  float s = 0.f;
  for (int i = lane; i < CONDDIM; i += 64) s += crow[i] * wrow[i];
#pragma unroll
  for (int m = 32; m > 0; m >>= 1) s += __shfl_xor(s, m, 64);
  if (lane == 0) cond[b * CH_ + c] = s + cpb[c];
}

// ---------------- counted-vmcnt implicit-GEMM conv ----------------
// A-tile LDS uses a chunk XOR swizzle (c' = lhi ^ ((row>>1)&3)) so each
// quarter-wave b128 read covers all 32 banks (2 dwords/bank) -- the linear
// stride-64B layout was a 4-way conflict (r11: 4.7M conflict cycles). Applied
// both-sides (rule #21): staging SOURCE offsets pre-swizzled, LDS dest linear,
// reads XOR the same mask. For 1x1 the mask is per-thread constant (folded
// into aAddr); for 3x3 it's computed per fragment (row varies with tap).
// 3x3: 3 taps/phase, B in THREE 12KB thirds staged TWO phases ahead.
// EPI: 0 = f32 NHWC (+bias); 2 = FINAL f32 NCHW vectorized (+bias+addf NHWC);
//      5 = QKV fused (seg: q bf16*QSCALE / k bf16 / vT bf16 KPOS-PERMUTED);
//      6 = conv1 + FUSED residual 1x1 (center tap af_[1], weights wp2/bias2 -> outf2)
template <int TAPS, int PIN, int EPI>
__global__ __launch_bounds__(256, 3) void conv_kernel(
    const u16* __restrict__ in, const u16* __restrict__ wp, const float* __restrict__ bias,
    float* __restrict__ outf, const float* __restrict__ addf,
    u16* __restrict__ o0, u16* __restrict__ o1, u16* __restrict__ o2,
    const float* __restrict__ b0, const float* __restrict__ b1, const float* __restrict__ b2,
    const u16* __restrict__ wp2, float* __restrict__ outf2, const float* __restrict__ bias2) {
  constexpr int LDSZ = (TAPS == 9) ? (2 * 14336 + 3 * 12288 + (EPI == 6 ? 2 * 4096 : 0))
                                   : (4 * 8192 + 4 * 4096);
  __shared__ char lds[LDSZ];
  char* ldsA = lds;
  char* ldsB = lds + ((TAPS == 9) ? 2 * 14336 : 4 * 8192);
  char* ldsR = lds + 2 * 14336 + 3 * 12288;   // only used when EPI==6

  const int b = blockIdx.z;
  int seg = 0, coy = blockIdx.y;
  if constexpr (EPI == 5) { seg = coy >> 3; coy &= 7; }
  const int co0 = coy * 64;
  const int p0 = blockIdx.x * 128;
  const int tid = threadIdx.x;
  const int lane = tid & 63, wid = tid >> 6;
  const int wv = wid >> 1, wc = wid & 1;
  const int l15 = lane & 15, lhi = lane >> 4;

  // global bases
  const char* aSrc;
  if constexpr (TAPS == 9) {
    aSrc = (const char*)in + ((size_t)b * PPB + (size_t)blockIdx.x * 4 * PR) * 1024;
  } else if constexpr (PIN) {
    aSrc = (const char*)in + (size_t)b * PPB * 1024;
  } else {
    aSrc = (const char*)in + ((size_t)b * NSP + p0) * 1024;
  }
  const char* bSrc = (const char*)wp + (size_t)((EPI == 5) ? seg * 524288 : 0) + co0 * 16;
  const char* rSrc = (const char*)wp2 + co0 * 16;   // EPI==6 only

  // per-thread staging source offsets (chunk pre-swizzled: c_src = (tid&3) ^ ((row>>1)&3))
  const int pB = ((tid >> 6) * 512 + (tid & 63)) * 16;
  int pA0, pA1, pA3 = 0;
  if constexpr (TAPS == 9) {
    int r0 = tid >> 2;
    int c0s = (tid & 3) ^ ((r0 >> 1) & 3);
    pA0 = (r0 << 10) + (c0s << 4);                                     // iters j: + j*65536 (row+64k: same swz)
    int r3 = 192 + ((tid & 127) >> 2);
    int c3s = (tid & 3) ^ ((r3 >> 1) & 3);
    pA3 = (r3 << 10) + (c3s << 4);                                     // iter 3 (dup waves 2,3)
    pA1 = 0;
  } else {
    int a0 = (tid >> 2), a1 = 64 + (tid >> 2);
    int cs = (tid & 3) ^ (((tid >> 2) >> 1) & 3);                      // LDS rows a0 and a0+64: same swz bits
    if constexpr (PIN) {
      int pp0 = p0 + a0, pp1 = p0 + a1;
      int g0 = ((pp0 >> 5) + 1) * PR + (pp0 & 31) + 1;
      int g1 = ((pp1 >> 5) + 1) * PR + (pp1 & 31) + 1;
      pA0 = (g0 << 10) + (cs << 4);
      pA1 = (g1 << 10) + (cs << 4);
    } else {
      pA0 = (a0 << 10) + (cs << 4);
      pA1 = (a1 << 10) + (cs << 4);
    }
  }

  // per-thread LDS read bases
  const int rowbA = (TAPS == 9) ? (wv * 68 + l15) : (wv * 64 + l15);
  // 1x1: row adders {0,16,32,48} and half offset 64 keep (row>>1)&3 -> fold swizzle into aAddr
  const int aAddr = rowbA * 64 + ((lhi ^ ((l15 >> 1) & 3)) << 4);      // valid for 1x1 path only
  const int bAddr = (lhi * 64 + wc * 32 + l15) * 16;

  f32x4 acc[4][2], accR[4][2];
#pragma unroll
  for (int m = 0; m < 4; m++)
#pragma unroll
    for (int n = 0; n < 2; n++) { acc[m][n] = {0.f, 0.f, 0.f, 0.f}; accR[m][n] = {0.f, 0.f, 0.f, 0.f}; }

  if constexpr (TAPS == 9) {
    // ---- prologue: A(kc0) fully + B thirds 0,1 (taps 0-5 of kc0) [+ R(kc0)] ----
    gload16(aSrc + pA0,          ldsA + (wid << 10));
    gload16(aSrc + pA0 + 65536,  ldsA + 4096 + (wid << 10));
    gload16(aSrc + pA0 + 131072, ldsA + 8192 + (wid << 10));
    gload16(aSrc + pA3,          ldsA + 12288 + ((wid & 1) << 10));
    gload16(bSrc + (size_t)(0 * 64) * 8192 + pB, ldsB + (wid << 10));                 // t0 -> third0
    gload16(bSrc + (size_t)(1 * 64) * 8192 + pB, ldsB + 4096 + (wid << 10));          // t1
    gload16(bSrc + (size_t)(2 * 64) * 8192 + pB, ldsB + 8192 + (wid << 10));          // t2
    gload16(bSrc + (size_t)(3 * 64) * 8192 + pB, ldsB + 12288 + (wid << 10));         // t3 -> third1
    gload16(bSrc + (size_t)(4 * 64) * 8192 + pB, ldsB + 12288 + 4096 + (wid << 10));  // t4
    gload16(bSrc + (size_t)(5 * 64) * 8192 + pB, ldsB + 12288 + 8192 + (wid << 10));  // t5
    if constexpr (EPI == 6) {
      gload16(rSrc + pB, ldsR + (wid << 10));                                         // R kc0 -> buf0
      VWAIT(4);   // A + third0 landed; third1(3)+R(1) may fly
    } else {
      VWAIT(3);   // A + third0 landed; third1(3) may fly
    }
    BARRIER;

// swizzled A fragment read: row = rowbA + K (K compile-time per fragment)
#define AREAD(Ab_, K) (*(const bf8*)((Ab_) + (rowbA + (K)) * 64 + ((lhi ^ (((rowbA + (K)) >> 1) & 3)) << 4)))

// phase (KC, T): consumes B third T, A buf AS; stages 2-phases-ahead B; A spread T0/T1/T2.
#define PH3(KC, T, AS) do {                                                             \
    const int kcn_ = ((KC) < 15) ? (KC) + 1 : 15;                                       \
    if constexpr ((T) == 0) {                                                           \
      gload16(bSrc + (size_t)(6 * 64 + (KC) * 4) * 8192 + pB, ldsB + 24576 + (wid << 10)); \
      gload16(bSrc + (size_t)(7 * 64 + (KC) * 4) * 8192 + pB, ldsB + 24576 + 4096 + (wid << 10)); \
      gload16(bSrc + (size_t)(8 * 64 + (KC) * 4) * 8192 + pB, ldsB + 24576 + 8192 + (wid << 10)); \
      gload16(aSrc + kcn_ * 64 + pA0,         ldsA + (1 - (AS)) * 14336 + (wid << 10)); \
      gload16(aSrc + kcn_ * 64 + pA0 + 65536, ldsA + (1 - (AS)) * 14336 + 4096 + (wid << 10)); \
    } else if constexpr ((T) == 1) {                                                    \
      gload16(bSrc + (size_t)(0 * 64 + kcn_ * 4) * 8192 + pB, ldsB + (wid << 10));      \
      gload16(bSrc + (size_t)(1 * 64 + kcn_ * 4) * 8192 + pB, ldsB + 4096 + (wid << 10)); \
      gload16(bSrc + (size_t)(2 * 64 + kcn_ * 4) * 8192 + pB, ldsB + 8192 + (wid << 10)); \
      gload16(aSrc + kcn_ * 64 + pA0 + 131072, ldsA + (1 - (AS)) * 14336 + 8192 + (wid << 10)); \
      if constexpr (EPI == 6)                                                           \
        if ((KC) < 15)                                                                  \
          gload16(rSrc + (size_t)kcn_ * 32768 + pB, ldsR + (kcn_ & 1) * 4096 + (wid << 10)); \
    } else {                                                                            \
      gload16(bSrc + (size_t)(3 * 64 + kcn_ * 4) * 8192 + pB, ldsB + 12288 + (wid << 10)); \
      gload16(bSrc + (size_t)(4 * 64 + kcn_ * 4) * 8192 + pB, ldsB + 12288 + 4096 + (wid << 10)); \
      gload16(bSrc + (size_t)(5 * 64 + kcn_ * 4) * 8192 + pB, ldsB + 12288 + 8192 + (wid << 10)); \
      gload16(aSrc + kcn_ * 64 + pA3, ldsA + (1 - (AS)) * 14336 + 12288 + ((wid & 1) << 10)); \
    }                                                                                   \
    SCHEDB;                                                                             \
    {                                                                                   \
      const char* Ab_ = ldsA + (AS) * 14336;                                            \
      const char* Bb_ = ldsB + (T) * 12288;                                             \
      bf8 af_[3][4], bq_[3][2];                                                         \
      _Pragma("unroll")                                                                 \
      for (int tt = 0; tt < 3; tt++) {                                                  \
        const int DT_ = (T) * 34 + tt;                                                  \
        af_[tt][0] = AREAD(Ab_, DT_ + 0);                                               \
        af_[tt][1] = AREAD(Ab_, DT_ + 16);                                              \
        af_[tt][2] = AREAD(Ab_, DT_ + 34);                                              \
        af_[tt][3] = AREAD(Ab_, DT_ + 50);                                              \
        bq_[tt][0] = *(const bf8*)(Bb_ + tt * 4096 + 0   + bAddr);                      \
        bq_[tt][1] = *(const bf8*)(Bb_ + tt * 4096 + 256 + bAddr);                      \
      }                                                                                 \
      __builtin_amdgcn_s_setprio(1);                                                    \
      _Pragma("unroll")                                                                 \
      for (int tt = 0; tt < 3; tt++)                                                    \
        _Pragma("unroll")                                                               \
        for (int m = 0; m < 4; m++) {                                                   \
          acc[m][0] = mfma_bf16(af_[tt][m], bq_[tt][0], acc[m][0]);                     \
          acc[m][1] = mfma_bf16(af_[tt][m], bq_[tt][1], acc[m][1]);                     \
        }                                                                               \
      if constexpr (EPI == 6 && (T) == 1) {                                             \
        bf8 rq0 = *(const bf8*)(ldsR + ((KC) & 1) * 4096 + 0   + bAddr);                \
        bf8 rq1 = *(const bf8*)(ldsR + ((KC) & 1) * 4096 + 256 + bAddr);                \
        _Pragma("unroll")                                                               \
        for (int m = 0; m < 4; m++) {                                                   \
          accR[m][0] = mfma_bf16(af_[1][m], rq0, accR[m][0]);                           \
          accR[m][1] = mfma_bf16(af_[1][m], rq1, accR[m][1]);                           \
        }                                                                               \
      }                                                                                 \
      __builtin_amdgcn_s_setprio(0);                                                    \
    }                                                                                   \
    if constexpr ((T) == 0) { VWAIT(5); }                                               \
    else if constexpr ((T) == 1) {                                                      \
      if constexpr (EPI == 6) { VWAIT(5); } else { VWAIT(4); }                          \
    } else { VWAIT(4); }                                                                \
    BARRIER;                                                                            \
  } while (0)

    for (int kc2 = 0; kc2 < 8; kc2++) {
      PH3(kc2 * 2,     0, 0); PH3(kc2 * 2,     1, 0); PH3(kc2 * 2,     2, 0);
      PH3(kc2 * 2 + 1, 0, 1); PH3(kc2 * 2 + 1, 1, 1); PH3(kc2 * 2 + 1, 2, 1);
    }
#undef PH3
#undef AREAD
  } else {
    // ---- prologue: A(0),B(0) then A(1),B(1) ----
    gload16(aSrc + pA0,         ldsA + (wid << 10));
    gload16(aSrc + pA1,         ldsA + 4096 + (wid << 10));
    gload16(bSrc + pB,          ldsB + (wid << 10));
    gload16(aSrc + 64 + pA0,    ldsA + 8192 + (wid << 10));
    gload16(aSrc + 64 + pA1,    ldsA + 8192 + 4096 + (wid << 10));
    gload16(bSrc + 32768 + pB,  ldsB + 4096 + (wid << 10));
    VWAIT(3);
    BARRIER;

#define PH1(KC, S) do {                                                                 \
    constexpr int S2 = ((S) + 2) & 3;                                                   \
    const int kcn_ = ((KC) + 2 < 16) ? (KC) + 2 : 15;                                   \
    gload16(bSrc + (size_t)kcn_ * 32768 + pB, ldsB + S2 * 4096 + (wid << 10));          \
    gload16(aSrc + kcn_ * 64 + pA0, ldsA + S2 * 8192 + (wid << 10));                    \
    gload16(aSrc + kcn_ * 64 + pA1, ldsA + S2 * 8192 + 4096 + (wid << 10));             \
    SCHEDB;                                                                             \
    bf8 af0 = *(const bf8*)(ldsA + (S) * 8192 + 0    + aAddr);                          \
    bf8 af1 = *(const bf8*)(ldsA + (S) * 8192 + 1024 + aAddr);                          \
    bf8 af2 = *(const bf8*)(ldsA + (S) * 8192 + 2048 + aAddr);                          \
    bf8 af3 = *(const bf8*)(ldsA + (S) * 8192 + 3072 + aAddr);                          \
    bf8 bq0 = *(const bf8*)(ldsB + (S) * 4096 + 0   + bAddr);                           \
    bf8 bq1 = *(const bf8*)(ldsB + (S) * 4096 + 256 + bAddr);                           \
    __builtin_amdgcn_s_setprio(1);                                                      \
    acc[0][0] = mfma_bf16(af0, bq0, acc[0][0]);                                         \
    acc[0][1] = mfma_bf16(af0, bq1, acc[0][1]);                                         \
    acc[1][0] = mfma_bf16(af1, bq0, acc[1][0]);                                         \
    acc[1][1] = mfma_bf16(af1, bq1, acc[1][1]);                                         \
    acc[2][0] = mfma_bf16(af2, bq0, acc[2][0]);                                         \
    acc[2][1] = mfma_bf16(af2, bq1, acc[2][1]);                                         \
    acc[3][0] = mfma_bf16(af3, bq0, acc[3][0]);                                         \
    acc[3][1] = mfma_bf16(af3, bq1, acc[3][1]);                                         \
    __builtin_amdgcn_s_setprio(0);                                                      \
    VWAIT(3);                                                                           \
    BARRIER;                                                                            \
  } while (0)

    for (int kc4 = 0; kc4 < 4; kc4++) {
      PH1(kc4 * 4 + 0, 0); PH1(kc4 * 4 + 1, 1); PH1(kc4 * 4 + 2, 2); PH1(kc4 * 4 + 3, 3);
    }
#undef PH1
  }

  VWAIT(0);   // drain stray prefetches before LDS teardown

  // ---- epilogue ----
#pragma unroll
  for (int m = 0; m < 4; m++) {
    int pbase = p0 + wv * 64 + m * 16 + lhi * 4;
#pragma unroll
    for (int n = 0; n < 2; n++) {
      int co = co0 + wc * 32 + n * 16 + l15;
      if constexpr (EPI == 0) {
        float bv = bias[co];
#pragma unroll
        for (int r = 0; r < 4; r++)
          outf[((size_t)b * NSP + pbase + r) * CH_ + co] = acc[m][n][r] + bv;
      } else if constexpr (EPI == 6) {
        float bv = bias[co];
        float rv = bias2[co];
#pragma unroll
        for (int r = 0; r < 4; r++) {
          size_t idx = ((size_t)b * NSP + pbase + r) * CH_ + co;
          outf[idx]  = acc[m][n][r] + bv;
          outf2[idx] = accR[m][n][r] + rv;
        }
      } else if constexpr (EPI == 2) {
        float bv = bias[co];
        f32x4 v;
#pragma unroll
        for (int r = 0; r < 4; r++)
          v[r] = acc[m][n][r] + bv + addf[((size_t)b * NSP + pbase + r) * CH_ + co];
        *(f32x4*)(outf + ((size_t)b * CH_ + co) * NSP + pbase) = v;
      } else {  // EPI == 5 (qkv)
        if (seg == 0) {
          float bv = b0[co];
#pragma unroll
          for (int r = 0; r < 4; r++)
            o0[((size_t)b * NSP + pbase + r) * CH_ + co] = f2bf((acc[m][n][r] + bv) * QSCALE);
        } else if (seg == 1) {
          float bv = b1[co];
#pragma unroll
          for (int r = 0; r < 4; r++)
            o1[((size_t)b * NSP + pbase + r) * CH_ + co] = f2bf(acc[m][n][r] + bv);
        } else {
          float bv = b2[co];
          union { bf4 v; u64 u; } pk4;
#pragma unroll
          for (int r = 0; r < 4; r++) pk4.v[r] = (short)f2bf(acc[m][n][r] + bv);
          int np = (pbase & ~31) | ((pbase & 12) << 1) | ((pbase & 16) >> 2);  // kpos permute
          *(u64*)(o2 + ((size_t)b * CH_ + co) * NSP + np) = pk4.u;
        }
      }
    }
  }
}

// ---------------- GroupNorm ----------------
// MODE 0: y = silu(gn(x))              -> outb (bf16, PADDED NHWC)
// MODE 1: y = gn(x)*(1+cond)+resid     -> outf (f32, may alias in) + outb (bf16 NHWC)
template <int MODE>
__global__ __launch_bounds__(256) void gn_kernel(
    const float* __restrict__ in, const float* __restrict__ gw, const float* __restrict__ gb,
    const float* __restrict__ cond, const float* __restrict__ resid,
    float* __restrict__ outf, u16* __restrict__ outb) {
  int b = blockIdx.y, g = blockIdx.x;
  int tid = threadIdx.x;
  int c = g * 8 + (tid & 7);
  int prow = tid >> 3;            // 0..31
  const float* base = in + (size_t)b * NSP * CH_ + c;
  float v[32];
  float s = 0.f, ss = 0.f;
#pragma unroll
  for (int i = 0; i < 32; i++) {
    v[i] = base[(size_t)(prow + i * 32) * CH_];
    s += v[i]; ss += v[i] * v[i];
  }
  __shared__ float rs[256], rss[256];
  rs[tid] = s; rss[tid] = ss;
  __syncthreads();
  for (int off = 128; off > 0; off >>= 1) {
    if (tid < off) { rs[tid] += rs[tid + off]; rss[tid] += rss[tid + off]; }
    __syncthreads();
  }
  float mean = rs[0] * (1.f / 8192.f);
  float var = rss[0] * (1.f / 8192.f) - mean * mean;
  float inv = rsqrtf(var + 1e-5f);
  float gamma = gw[c], beta = gb[c];
  float cm = 0.f;
  if (MODE == 1) cm = 1.f + cond[b * CH_ + c];
#pragma unroll
  for (int i = 0; i < 32; i++) {
    int p = prow + i * 32;
    float y = (v[i] - mean) * inv * gamma + beta;
    if (MODE == 0) {
      float sg = 1.f / (1.f + __expf(-y));
      int yy = p >> 5, xc = p & 31;
      outb[((size_t)b * PPB + (size_t)(yy + 1) * PR + xc + 1) * CH_ + c] = f2bf(y * sg);
    } else {
      size_t idx = ((size_t)b * NSP + p) * CH_ + c;
      float z = y * cm + resid[idx];
      outf[idx] = z;
      outb[idx] = f2bf(z);
    }
  }
}

// ---------------- flash attention (2-tile pipeline, no-max exp2 softmax) ----------------
// 128 q-rows/block (4 waves x 32 q), grid 512, 16 KV tiles, 3-buffer LDS.
// Row-sum via MFMA ones-trick; V kpos-permuted so each PV B-fragment is one b128.
__global__ __launch_bounds__(256, 2) void attn_kernel(const u16* __restrict__ q, const u16* __restrict__ k,
                                                      const u16* __restrict__ vT, u16* __restrict__ ao) {
  int bid = blockIdx.x;
  int swz = (bid & 7) * 64 + (bid >> 3);   // XCD-bijective: each XCD owns one batch
  int b = swz >> 6;
  int head = (swz >> 3) & 7;
  int qt = swz & 7;
  int tid = threadIdx.x, lane = tid & 63, wid = tid >> 6;
  int l15 = lane & 15, lhi = lane >> 4;
  int cb = head * HD;
  int q0 = qt * 128 + wid * 32;

  const char* qp = (const char*)(q + (size_t)b * NSP * CH_ + cb);
  const char* kp = (const char*)(k + (size_t)b * NSP * CH_ + cb);
  const char* vp = (const char*)(vT + ((size_t)b * CH_ + cb) * NSP);

  __shared__ u16 Ksh[3][64 * 64];   // 24 KB
  __shared__ u16 Vsh[3][64 * 64];   // 24 KB

  bf8 aq[2][2];
#pragma unroll
  for (int qh = 0; qh < 2; qh++)
#pragma unroll
    for (int ks = 0; ks < 2; ks++)
      aq[qh][ks] = *(const bf8*)(qp + ((size_t)(q0 + qh * 16 + l15) * CH_ + ks * 32 + lhi * 8) * 2);

  const bf8 ones8 = {16256, 16256, 16256, 16256, 16256, 16256, 16256, 16256};  // bf16 1.0 x8

  f32x4 o[2][4], osum[2];
#pragma unroll
  for (int qh = 0; qh < 2; qh++) {
    osum[qh] = {0.f, 0.f, 0.f, 0.f};
#pragma unroll
    for (int n = 0; n < 4; n++) o[qh][n] = {0.f, 0.f, 0.f, 0.f};
  }

  auto stage = [&](int kt, int buf) {
#pragma unroll
    for (int t = 0; t < 2; t++) {
      int i = wid * 2 + t;
      int chunk = i * 64 + lane;             // 0..511
      int r = chunk >> 3, c = chunk & 7;
      gload16(kp + (size_t)(kt * 64 + r) * 1024 + (size_t)((c ^ (r & 7)) * 16),
              (char*)Ksh[buf] + i * 1024);
    }
#pragma unroll
    for (int t = 0; t < 2; t++) {
      int i = wid * 2 + t;
      int chunk = i * 64 + lane;
      int r = chunk >> 3, c = chunk & 7;     // r = d row of V^T
      gload16(vp + (size_t)r * 2048 + (size_t)(kt * 128) + (size_t)((c ^ (r & 7)) * 16),
              (char*)Vsh[buf] + i * 1024);
    }
  };

  // QK^T (swapped) for one tile: sacc[qh][kf], elem r <-> kpos = kf*16+lhi*4+r, q=q0+qh*16+l15
  auto qk = [&](int buf, f32x4 (&sacc)[2][4]) {
    const char* Kb = (const char*)Ksh[0] + buf * 8192;
#pragma unroll
    for (int qh = 0; qh < 2; qh++)
#pragma unroll
      for (int kf = 0; kf < 4; kf++) sacc[qh][kf] = {0.f, 0.f, 0.f, 0.f};
#pragma unroll
    for (int kf = 0; kf < 4; kf++) {
      bf8 ak[2];
#pragma unroll
      for (int ks = 0; ks < 2; ks++)
        ak[ks] = *(const bf8*)(Kb + (size_t)(kf * 16 + l15) * 128 + (((ks * 4 + lhi) ^ (l15 & 7)) * 16));
#pragma unroll
      for (int qh = 0; qh < 2; qh++)
#pragma unroll
        for (int ks = 0; ks < 2; ks++)
          sacc[qh][kf] = mfma_bf16(ak[ks], aq[qh][ks], sacc[qh][kf]);
    }
  };

  // P = exp2(S) (no max), PV + MFMA row-sum
  auto smpv = [&](int buf, f32x4 (&sacc)[2][4]) {
    const char* Vb = (const char*)Vsh[0] + buf * 8192;
    unsigned pk[2][4][2];
#pragma unroll
    for (int qh = 0; qh < 2; qh++)
#pragma unroll
      for (int kf = 0; kf < 4; kf++) {
        f32x4 pv;
#pragma unroll
        for (int r = 0; r < 4; r++) pv[r] = exp2f(sacc[qh][kf][r]);
        pk[qh][kf][0] = cvt_pk_bf16(pv[0], pv[1]);
        pk[qh][kf][1] = cvt_pk_bf16(pv[2], pv[3]);
      }
#pragma unroll
    for (int g = 0; g < 2; g++) {
      union { bf8 v8; unsigned u[4]; } ap[2];
#pragma unroll
      for (int qh = 0; qh < 2; qh++) {
        ap[qh].u[0] = pk[qh][2 * g][0];
        ap[qh].u[1] = pk[qh][2 * g][1];
        ap[qh].u[2] = pk[qh][2 * g + 1][0];
        ap[qh].u[3] = pk[qh][2 * g + 1][1];
      }
#pragma unroll
      for (int nf2 = 0; nf2 < 4; nf2++) {
        int row = nf2 * 16 + l15;
        bf8 bv8 = *(const bf8*)(Vb + (size_t)row * 128 + (((4 * g + lhi) ^ (l15 & 7)) * 16));
#pragma unroll
        for (int qh = 0; qh < 2; qh++)
          o[qh][nf2] = mfma_bf16(ap[qh].v8, bv8, o[qh][nf2]);
      }
#pragma unroll
      for (int qh = 0; qh < 2; qh++)
        osum[qh] = mfma_bf16(ap[qh].v8, ones8, osum[qh]);   // row sums of P
    }
  };

  stage(0, 0);
  stage(1, 1);
  VWAIT(4);        // stage(0) complete; stage(1) may remain in flight
  BARRIER;

  f32x4 saccA[2][4], saccB[2][4];
  qk(0, saccA);    // tile 0

  int bc = 0;      // buffer holding current tile kt
  for (int kt2 = 0; kt2 < 8; kt2++) {
    {  // even tile kt = 2*kt2: cur = saccA, next -> saccB
      int kt = 2 * kt2;
      int bn = (bc == 2) ? 0 : bc + 1;
      int bs = (bn == 2) ? 0 : bn + 1;
      VWAIT(0);                         // stage(kt+1) landed (only outstanding)
      BARRIER;                          // all waves past PV(kt-1)
      qk(bn, saccB);                    // QK(kt+1): MFMAs in flight during softmax(kt)
      if (kt < 14) stage(kt + 2, bs);
      smpv(bc, saccA);
      bc = bn;
    }
    {  // odd tile kt = 2*kt2+1: cur = saccB, next -> saccA
      int kt = 2 * kt2 + 1;
      if (kt < 15) {
        int bn = (bc == 2) ? 0 : bc + 1;
        int bs = (bn == 2) ? 0 : bn + 1;
        VWAIT(0);
        BARRIER;
        qk(bn, saccA);
        if (kt < 14) stage(kt + 2, bs);
        smpv(bc, saccB);
        bc = bn;
      } else {
        smpv(bc, saccB);                // tile 15: data staged & drained earlier
      }
    }
  }

  // epilogue: osum rows already match this lane's O rows -> no cross-lane ops
#pragma unroll
  for (int qh = 0; qh < 2; qh++) {
    float linv[4];
#pragma unroll
    for (int r = 0; r < 4; r++) linv[r] = 1.f / osum[qh][r];
#pragma unroll
    for (int nf2 = 0; nf2 < 4; nf2++)
#pragma unroll
      for (int r = 0; r < 4; r++) {
        float val = o[qh][nf2][r] * linv[r];
        ao[((size_t)b * NSP + q0 + qh * 16 + lhi * 4 + r) * CH_ + cb + nf2 * 16 + l15] = f2bf(val);
      }
  }
}

// ---------------- launch ----------------

extern "C" void kernel_launch(void* const* d_in, const int* in_sizes, int n_in,
                              void* d_out, int out_size, void* d_ws, size_t ws_size,
                              hipStream_t stream) {
  const float* x    = (const float*)d_in[0];
  const float* cnd  = (const float*)d_in[1];
  const float* c1w  = (const float*)d_in[2];
  const float* c1b  = (const float*)d_in[3];
  const float* g1w  = (const float*)d_in[4];
  const float* g1b  = (const float*)d_in[5];
  const float* c2w  = (const float*)d_in[6];
  const float* c2b  = (const float*)d_in[7];
  const float* g2w  = (const float*)d_in[8];
  const float* g2b  = (const float*)d_in[9];
  const float* cpw  = (const float*)d_in[10];
  const float* cpb  = (const float*)d_in[11];
  const float* rpw  = (const float*)d_in[12];
  const float* rpb  = (const float*)d_in[13];
  const float* qw   = (const float*)d_in[14];
  const float* qb   = (const float*)d_in[15];
  const float* kw   = (const float*)d_in[16];
  const float* kb   = (const float*)d_in[17];
  const float* vw   = (const float*)d_in[18];
  const float* vb   = (const float*)d_in[19];
  const float* ow   = (const float*)d_in[20];
  const float* ob   = (const float*)d_in[21];
  float* out = (float*)d_out;

  char* ws = (char*)d_ws;
  size_t off = 0;
  auto alloc = [&](size_t bytes) -> char* {
    char* p = ws + off;
    off = (off + bytes + 255) & ~(size_t)255;
    return p;
  };
  const size_t ACT_F = (size_t)NB * NSP * CH_ * 4;   // 16 MB
  const size_t ACT_B = (size_t)NB * NSP * CH_ * 2;   // 8 MB
  const size_t PAD_B = (size_t)NB * PPB * CH_ * 2;   // 9.47 MB

  u16* xp    = (u16*)alloc(PAD_B);               // x padded NHWC bf16
  u16* h1p   = (u16*)alloc(PAD_B);               // silu(gn1) padded bf16
  u16* w1p   = (u16*)alloc((size_t)9 * CH_ * CH_ * 2);
  u16* w2p   = (u16*)alloc((size_t)9 * CH_ * CH_ * 2);
  u16* wrp   = (u16*)alloc((size_t)CH_ * CH_ * 2);
  u16* wqkv  = (u16*)alloc((size_t)3 * CH_ * CH_ * 2);
  u16* wop   = (u16*)alloc((size_t)CH_ * CH_ * 2);
  float* cndv = (float*)alloc((size_t)NB * CH_ * 4);
  float* resid = (float*)alloc(ACT_F);           // residual f32 NHWC
  float* h12  = (float*)alloc(ACT_F);            // conv outs; gn2 in-place -> h (f32)
  u16* hb    = (u16*)alloc(ACT_B);               // h bf16 (attn input)
  u16* qbuf  = (u16*)alloc(ACT_B);               // Q (pre-scaled, exp2 domain) NHWC bf16
  u16* kbuf  = (u16*)alloc(ACT_B);               // K NHWC bf16
  u16* vTb   = (u16*)alloc(ACT_B);               // V^T [B][512][1024] bf16, kpos-permuted
  u16* aob   = (u16*)alloc(ACT_B);               // attention out bf16
  if (off > ws_size) return;

  dim3 tgrid(NSP / 32, CH_ / 32, NB);
  border_zero_kernel<<<(NB * 132 * 64 + 255) / 256, 256, 0, stream>>>(xp, h1p);
  pack_x_kernel<<<tgrid, 1024, 0, stream>>>(x, xp);
  pack_w3_kernel<<<dim3((9 * 64 * CH_ + 255) / 256, 2), 256, 0, stream>>>(c1w, c2w, w1p, w2p);
  pack_w1_kernel<<<dim3((64 * CH_) / 256, 5), 256, 0, stream>>>(
      rpw, qw, kw, vw, ow,
      wrp, wqkv, wqkv + (size_t)CH_ * CH_, wqkv + (size_t)2 * CH_ * CH_, wop);
  cond_kernel<<<dim3(CH_ / 4, NB), 256, 0, stream>>>(cnd, cpw, cpb, cndv);

  dim3 ggrid(NSP / 128, CH_ / 64, NB);
  dim3 qgrid(NSP / 128, 3 * CH_ / 64, NB);
  // conv1 (3x3) + FUSED residual proj -> h12 f32, resid f32
  conv_kernel<9, 1, 6><<<ggrid, 256, 0, stream>>>(xp, w1p, c1b, h12, nullptr,
                                                  nullptr, nullptr, nullptr, nullptr, nullptr, nullptr,
                                                  wrp, resid, rpb);
  // gn1 + silu -> h1p (padded bf16)
  gn_kernel<0><<<dim3(NGROUP, NB), 256, 0, stream>>>(h12, g1w, g1b, nullptr, nullptr, nullptr, h1p);
  // conv2 (3x3) -> h12 f32
  conv_kernel<9, 1, 0><<<ggrid, 256, 0, stream>>>(h1p, w2p, c2b, h12, nullptr,
                                                  nullptr, nullptr, nullptr, nullptr, nullptr, nullptr,
                                                  nullptr, nullptr, nullptr);
  // gn2 * (1+cond) + resid -> h12 (in-place f32), hb bf16
  gn_kernel<1><<<dim3(NGROUP, NB), 256, 0, stream>>>(h12, g2w, g2b, cndv, resid, h12, hb);
  // fused q/k/vT (1x1)
  conv_kernel<1, 0, 5><<<qgrid, 256, 0, stream>>>(hb, wqkv, nullptr, nullptr, nullptr,
                                                  qbuf, kbuf, vTb, qb, kb, vb,
                                                  nullptr, nullptr, nullptr);
  // attention -> aob bf16 NHWC
  attn_kernel<<<512, 256, 0, stream>>>(qbuf, kbuf, vTb, aob);
  // out proj + bias + h -> d_out NCHW f32 directly
  conv_kernel<1, 0, 2><<<ggrid, 256, 0, stream>>>(aob, wop, ob, out, h12,
                                                  nullptr, nullptr, nullptr, nullptr, nullptr, nullptr,
                                                  nullptr, nullptr, nullptr);
}

// Round 13
// 221.336 us; speedup vs baseline: 1.0805x; 1.0805x over previous
//
#include <hip/hip_runtime.h>
#include <hip/hip_bf16.h>

typedef unsigned short u16;
typedef unsigned long long u64;
typedef __attribute__((ext_vector_type(8))) short bf8;   // 8 bf16 (raw bits, 4 VGPRs)
typedef __attribute__((ext_vector_type(4))) short bf4;   // 4 bf16 (2 VGPRs)
typedef __attribute__((ext_vector_type(4))) float f32x4;

#define CH_ 512
#define NSP 1024      // 32*32 spatial
#define NB 8
#define CONDDIM 1280
#define NGROUP 64     // 512/8
#define HEADS_ 8
#define HD 64         // head dim
#define PR 34         // padded row length (32 + 2)
#define PPB (PR*PR)   // padded positions per batch = 1156
#define QSCALE 0.18033688011112042f   // 0.125 * log2(e): softmax in exp2 domain

#define VWAIT(N) asm volatile("s_waitcnt vmcnt(" #N ")" ::: "memory")
#define SCHEDB __builtin_amdgcn_sched_barrier(0)
#define BARRIER do { SCHEDB; __builtin_amdgcn_s_barrier(); SCHEDB; } while (0)

__device__ __forceinline__ u16 f2bf(float f) {
  union { float f; unsigned u; } v; v.f = f;
  unsigned u = v.u;
  return (u16)((u + 0x7fffu + ((u >> 16) & 1u)) >> 16);   // RNE
}

__device__ __forceinline__ float b2f(u16 x) {
  union { unsigned u; float f; } v; v.u = ((unsigned)x) << 16; return v.f;
}

__device__ __forceinline__ unsigned cvt_pk_bf16(float lo, float hi) {
  unsigned r;
  asm volatile("v_cvt_pk_bf16_f32 %0, %1, %2" : "=v"(r) : "v"(lo), "v"(hi));
  return r;
}

__device__ __forceinline__ f32x4 mfma_bf16(bf8 a, bf8 b, f32x4 c) {
  return __builtin_amdgcn_mfma_f32_16x16x32_bf16(a, b, c, 0, 0, 0);
}

__device__ __forceinline__ void gload16(const void* g, void* l) {
  __builtin_amdgcn_global_load_lds((const __attribute__((address_space(1))) void*)g,
                                   (__attribute__((address_space(3))) void*)l, 16, 0, 0);
}

// ---------------- merged prologue kernel ----------------
// blockIdx ranges (256 threads each):
//   [0,4096)      pack_x: NCHW f32 -> padded NHWC bf16 (interior)
//   [4096,4360)   border zero xp & h1p         (264*256 == 8*132*64 exactly)
//   [4360,6664)   pack both 3x3 weights        (2*1152*256 == 2*9*64*512)
//   [6664,7304)   pack five 1x1 weights        (5*128*256 == 5*64*512)
//   [7304,8328)   cond GEMV                    (8*128 blocks)
__global__ __launch_bounds__(256) void prep_kernel(
    const float* __restrict__ x, u16* __restrict__ xp, u16* __restrict__ h1p,
    const float* __restrict__ c1w, const float* __restrict__ c2w,
    u16* __restrict__ w1p, u16* __restrict__ w2p,
    const float* __restrict__ rpw, const float* __restrict__ qw, const float* __restrict__ kw,
    const float* __restrict__ vw, const float* __restrict__ ow,
    u16* __restrict__ wrp, u16* __restrict__ wq, u16* __restrict__ wk,
    u16* __restrict__ wv, u16* __restrict__ wo,
    const float* __restrict__ cd, const float* __restrict__ cpw,
    const float* __restrict__ cpb, float* __restrict__ cond) {
  __shared__ float t[32][33];
  int bid = blockIdx.x;
  int tid = threadIdx.x;
  if (bid < 4096) {
    int px = bid & 31, py = (bid >> 5) & 15, b = bid >> 9;
    int c0 = py * 32, p0 = px * 32;
    int tx = tid & 31, ty = tid >> 5;
#pragma unroll
    for (int i = 0; i < 4; i++) {
      int row = ty + i * 8;
      t[row][tx] = x[((size_t)b * CH_ + c0 + row) * NSP + p0 + tx];
    }
    __syncthreads();
#pragma unroll
    for (int i = 0; i < 4; i++) {
      int pr = ty + i * 8;
      int p = p0 + pr;
      int y = p >> 5, xc = p & 31;
      xp[((size_t)b * PPB + (size_t)(y + 1) * PR + xc + 1) * CH_ + c0 + tx] = f2bf(t[tx][pr]);
    }
  } else if (bid < 4360) {
    int id = (bid - 4096) * 256 + tid;      // < 67584 == NB*132*64 exactly
    int ch8 = id & 63;
    int rest = id >> 6;
    int bidx = rest % 132;
    int bb = rest / 132;
    int r, c;
    if (bidx < 34)       { r = 0;          c = bidx; }
    else if (bidx < 68)  { r = 33;         c = bidx - 34; }
    else if (bidx < 100) { r = bidx - 67;  c = 0; }
    else                 { r = bidx - 99;  c = 33; }
    size_t off = ((size_t)bb * PPB + (size_t)r * PR + c) * CH_ + ch8 * 8;
    const bf8 z = {0, 0, 0, 0, 0, 0, 0, 0};
    *(bf8*)(xp + off) = z;
    *(bf8*)(h1p + off) = z;
  } else if (bid < 6664) {
    int id2 = bid - 4360;
    int which = (id2 >= 1152) ? 1 : 0;
    int id = (id2 - which * 1152) * 256 + tid;   // < 294912 == 9*64*512 exactly
    const float* w = which ? c2w : c1w;
    u16* wp = which ? w2p : w1p;
    int co = id & (CH_ - 1);
    int cib = (id >> 9) & 63;
    int tt = id >> 15;
    int dy = tt / 3, dx = tt % 3;
    bf8 v;
#pragma unroll
    for (int j = 0; j < 8; j++) {
      int ci = cib * 8 + j;
      v[j] = (short)f2bf(w[(((size_t)co * CH_ + ci) * 3 + dy) * 3 + dx]);
    }
    *(bf8*)(wp + ((size_t)(tt * 64 + cib) * CH_ + co) * 8) = v;
  } else if (bid < 7304) {
    int id3 = bid - 6664;
    int which = id3 >> 7;                   // 0..4
    int id = (id3 & 127) * 256 + tid;       // < 32768 == 64*512 exactly
    const float* w; u16* wp;
    switch (which) {
      case 0: w = rpw; wp = wrp; break;
      case 1: w = qw;  wp = wq;  break;
      case 2: w = kw;  wp = wk;  break;
      case 3: w = vw;  wp = wv;  break;
      default: w = ow; wp = wo;  break;
    }
    int co = id & (CH_ - 1);
    int cib = id >> 9;
    bf8 v;
#pragma unroll
    for (int j = 0; j < 8; j++) v[j] = (short)f2bf(w[(size_t)co * CH_ + cib * 8 + j]);
    *(bf8*)(wp + ((size_t)cib * CH_ + co) * 8) = v;
  } else {
    int id4 = bid - 7304;
    int b = id4 >> 7;
    int c = (id4 & 127) * 4 + (tid >> 6);
    int lane = tid & 63;
    const float* wrow = cpw + (size_t)c * CONDDIM;
    const float* crow = cd + (size_t)b * CONDDIM;
    float s = 0.f;
    for (int i = lane; i < CONDDIM; i += 64) s += crow[i] * wrow[i];
#pragma unroll
    for (int m = 32; m > 0; m >>= 1) s += __shfl_xor(s, m, 64);
    if (lane == 0) cond[b * CH_ + c] = s + cpb[c];
  }
}

// ---------------- counted-vmcnt implicit-GEMM conv ----------------
// A-tile LDS chunk XOR swizzle (c' = lhi ^ ((row>>1)&3)), both-sides (rule #21).
// 3x3: 3 taps/phase, B in THREE 12KB thirds staged TWO phases ahead.
// EPI: 2 = FINAL f32 NCHW vectorized (+bias+addf NHWC);
//      5 = QKV fused (seg: q bf16*QSCALE / k bf16 / vT bf16 KPOS-PERMUTED);
//      7 = bf16 NHWC out (+bias)                        [conv2]
//      8 = conv1: bf16 NHWC out + FUSED residual 1x1 (center tap, wp2/bias2 -> outf2 f32)
template <int TAPS, int PIN, int EPI>
__global__ __launch_bounds__(256, 3) void conv_kernel(
    const u16* __restrict__ in, const u16* __restrict__ wp, const float* __restrict__ bias,
    float* __restrict__ outf, const float* __restrict__ addf,
    u16* __restrict__ o0, u16* __restrict__ o1, u16* __restrict__ o2,
    const float* __restrict__ b0, const float* __restrict__ b1, const float* __restrict__ b2,
    const u16* __restrict__ wp2, float* __restrict__ outf2, const float* __restrict__ bias2) {
  constexpr int LDSZ = (TAPS == 9) ? (2 * 14336 + 3 * 12288 + (EPI == 8 ? 2 * 4096 : 0))
                                   : (4 * 8192 + 4 * 4096);
  __shared__ char lds[LDSZ];
  char* ldsA = lds;
  char* ldsB = lds + ((TAPS == 9) ? 2 * 14336 : 4 * 8192);
  char* ldsR = lds + 2 * 14336 + 3 * 12288;   // only used when EPI==8

  const int b = blockIdx.z;
  int seg = 0, coy = blockIdx.y;
  if constexpr (EPI == 5) { seg = coy >> 3; coy &= 7; }
  const int co0 = coy * 64;
  const int p0 = blockIdx.x * 128;
  const int tid = threadIdx.x;
  const int lane = tid & 63, wid = tid >> 6;
  const int wv = wid >> 1, wc = wid & 1;
  const int l15 = lane & 15, lhi = lane >> 4;

  // global bases
  const char* aSrc;
  if constexpr (TAPS == 9) {
    aSrc = (const char*)in + ((size_t)b * PPB + (size_t)blockIdx.x * 4 * PR) * 1024;
  } else if constexpr (PIN) {
    aSrc = (const char*)in + (size_t)b * PPB * 1024;
  } else {
    aSrc = (const char*)in + ((size_t)b * NSP + p0) * 1024;
  }
  const char* bSrc = (const char*)wp + (size_t)((EPI == 5) ? seg * 524288 : 0) + co0 * 16;
  const char* rSrc = (const char*)wp2 + co0 * 16;   // EPI==8 only

  // per-thread staging source offsets (chunk pre-swizzled: c_src = (tid&3) ^ ((row>>1)&3))
  const int pB = ((tid >> 6) * 512 + (tid & 63)) * 16;
  int pA0, pA1, pA3 = 0;
  if constexpr (TAPS == 9) {
    int r0 = tid >> 2;
    int c0s = (tid & 3) ^ ((r0 >> 1) & 3);
    pA0 = (r0 << 10) + (c0s << 4);
    int r3 = 192 + ((tid & 127) >> 2);
    int c3s = (tid & 3) ^ ((r3 >> 1) & 3);
    pA3 = (r3 << 10) + (c3s << 4);
    pA1 = 0;
  } else {
    int a0 = (tid >> 2), a1 = 64 + (tid >> 2);
    int cs = (tid & 3) ^ (((tid >> 2) >> 1) & 3);
    if constexpr (PIN) {
      int pp0 = p0 + a0, pp1 = p0 + a1;
      int g0 = ((pp0 >> 5) + 1) * PR + (pp0 & 31) + 1;
      int g1 = ((pp1 >> 5) + 1) * PR + (pp1 & 31) + 1;
      pA0 = (g0 << 10) + (cs << 4);
      pA1 = (g1 << 10) + (cs << 4);
    } else {
      pA0 = (a0 << 10) + (cs << 4);
      pA1 = (a1 << 10) + (cs << 4);
    }
  }

  // per-thread LDS read bases
  const int rowbA = (TAPS == 9) ? (wv * 68 + l15) : (wv * 64 + l15);
  const int aAddr = rowbA * 64 + ((lhi ^ ((l15 >> 1) & 3)) << 4);      // 1x1 path only
  const int bAddr = (lhi * 64 + wc * 32 + l15) * 16;

  f32x4 acc[4][2], accR[4][2];
#pragma unroll
  for (int m = 0; m < 4; m++)
#pragma unroll
    for (int n = 0; n < 2; n++) { acc[m][n] = {0.f, 0.f, 0.f, 0.f}; accR[m][n] = {0.f, 0.f, 0.f, 0.f}; }

  if constexpr (TAPS == 9) {
    // ---- prologue: A(kc0) fully + B thirds 0,1 (taps 0-5 of kc0) [+ R(kc0)] ----
    gload16(aSrc + pA0,          ldsA + (wid << 10));
    gload16(aSrc + pA0 + 65536,  ldsA + 4096 + (wid << 10));
    gload16(aSrc + pA0 + 131072, ldsA + 8192 + (wid << 10));
    gload16(aSrc + pA3,          ldsA + 12288 + ((wid & 1) << 10));
    gload16(bSrc + (size_t)(0 * 64) * 8192 + pB, ldsB + (wid << 10));
    gload16(bSrc + (size_t)(1 * 64) * 8192 + pB, ldsB + 4096 + (wid << 10));
    gload16(bSrc + (size_t)(2 * 64) * 8192 + pB, ldsB + 8192 + (wid << 10));
    gload16(bSrc + (size_t)(3 * 64) * 8192 + pB, ldsB + 12288 + (wid << 10));
    gload16(bSrc + (size_t)(4 * 64) * 8192 + pB, ldsB + 12288 + 4096 + (wid << 10));
    gload16(bSrc + (size_t)(5 * 64) * 8192 + pB, ldsB + 12288 + 8192 + (wid << 10));
    if constexpr (EPI == 8) {
      gload16(rSrc + pB, ldsR + (wid << 10));
      VWAIT(4);
    } else {
      VWAIT(3);
    }
    BARRIER;

// swizzled A fragment read: row = rowbA + K (K compile-time per fragment)
#define AREAD(Ab_, K) (*(const bf8*)((Ab_) + (rowbA + (K)) * 64 + ((lhi ^ (((rowbA + (K)) >> 1) & 3)) << 4)))

#define PH3(KC, T, AS) do {                                                             \
    const int kcn_ = ((KC) < 15) ? (KC) + 1 : 15;                                       \
    if constexpr ((T) == 0) {                                                           \
      gload16(bSrc + (size_t)(6 * 64 + (KC) * 4) * 8192 + pB, ldsB + 24576 + (wid << 10)); \
      gload16(bSrc + (size_t)(7 * 64 + (KC) * 4) * 8192 + pB, ldsB + 24576 + 4096 + (wid << 10)); \
      gload16(bSrc + (size_t)(8 * 64 + (KC) * 4) * 8192 + pB, ldsB + 24576 + 8192 + (wid << 10)); \
      gload16(aSrc + kcn_ * 64 + pA0,         ldsA + (1 - (AS)) * 14336 + (wid << 10)); \
      gload16(aSrc + kcn_ * 64 + pA0 + 65536, ldsA + (1 - (AS)) * 14336 + 4096 + (wid << 10)); \
    } else if constexpr ((T) == 1) {                                                    \
      gload16(bSrc + (size_t)(0 * 64 + kcn_ * 4) * 8192 + pB, ldsB + (wid << 10));      \
      gload16(bSrc + (size_t)(1 * 64 + kcn_ * 4) * 8192 + pB, ldsB + 4096 + (wid << 10)); \
      gload16(bSrc + (size_t)(2 * 64 + kcn_ * 4) * 8192 + pB, ldsB + 8192 + (wid << 10)); \
      gload16(aSrc + kcn_ * 64 + pA0 + 131072, ldsA + (1 - (AS)) * 14336 + 8192 + (wid << 10)); \
      if constexpr (EPI == 8)                                                           \
        if ((KC) < 15)                                                                  \
          gload16(rSrc + (size_t)kcn_ * 32768 + pB, ldsR + (kcn_ & 1) * 4096 + (wid << 10)); \
    } else {                                                                            \
      gload16(bSrc + (size_t)(3 * 64 + kcn_ * 4) * 8192 + pB, ldsB + 12288 + (wid << 10)); \
      gload16(bSrc + (size_t)(4 * 64 + kcn_ * 4) * 8192 + pB, ldsB + 12288 + 4096 + (wid << 10)); \
      gload16(bSrc + (size_t)(5 * 64 + kcn_ * 4) * 8192 + pB, ldsB + 12288 + 8192 + (wid << 10)); \
      gload16(aSrc + kcn_ * 64 + pA3, ldsA + (1 - (AS)) * 14336 + 12288 + ((wid & 1) << 10)); \
    }                                                                                   \
    SCHEDB;                                                                             \
    {                                                                                   \
      const char* Ab_ = ldsA + (AS) * 14336;                                            \
      const char* Bb_ = ldsB + (T) * 12288;                                             \
      bf8 af_[3][4], bq_[3][2];                                                         \
      _Pragma("unroll")                                                                 \
      for (int tt = 0; tt < 3; tt++) {                                                  \
        const int DT_ = (T) * 34 + tt;                                                  \
        af_[tt][0] = AREAD(Ab_, DT_ + 0);                                               \
        af_[tt][1] = AREAD(Ab_, DT_ + 16);                                              \
        af_[tt][2] = AREAD(Ab_, DT_ + 34);                                              \
        af_[tt][3] = AREAD(Ab_, DT_ + 50);                                              \
        bq_[tt][0] = *(const bf8*)(Bb_ + tt * 4096 + 0   + bAddr);                      \
        bq_[tt][1] = *(const bf8*)(Bb_ + tt * 4096 + 256 + bAddr);                      \
      }                                                                                 \
      __builtin_amdgcn_s_setprio(1);                                                    \
      _Pragma("unroll")                                                                 \
      for (int tt = 0; tt < 3; tt++)                                                    \
        _Pragma("unroll")                                                               \
        for (int m = 0; m < 4; m++) {                                                   \
          acc[m][0] = mfma_bf16(af_[tt][m], bq_[tt][0], acc[m][0]);                     \
          acc[m][1] = mfma_bf16(af_[tt][m], bq_[tt][1], acc[m][1]);                     \
        }                                                                               \
      if constexpr (EPI == 8 && (T) == 1) {                                             \
        bf8 rq0 = *(const bf8*)(ldsR + ((KC) & 1) * 4096 + 0   + bAddr);                \
        bf8 rq1 = *(const bf8*)(ldsR + ((KC) & 1) * 4096 + 256 + bAddr);                \
        _Pragma("unroll")                                                               \
        for (int m = 0; m < 4; m++) {                                                   \
          accR[m][0] = mfma_bf16(af_[1][m], rq0, accR[m][0]);                           \
          accR[m][1] = mfma_bf16(af_[1][m], rq1, accR[m][1]);                           \
        }                                                                               \
      }                                                                                 \
      __builtin_amdgcn_s_setprio(0);                                                    \
    }                                                                                   \
    if constexpr ((T) == 0) { VWAIT(5); }                                               \
    else if constexpr ((T) == 1) {                                                      \
      if constexpr (EPI == 8) { VWAIT(5); } else { VWAIT(4); }                          \
    } else { VWAIT(4); }                                                                \
    BARRIER;                                                                            \
  } while (0)

    for (int kc2 = 0; kc2 < 8; kc2++) {
      PH3(kc2 * 2,     0, 0); PH3(kc2 * 2,     1, 0); PH3(kc2 * 2,     2, 0);
      PH3(kc2 * 2 + 1, 0, 1); PH3(kc2 * 2 + 1, 1, 1); PH3(kc2 * 2 + 1, 2, 1);
    }
#undef PH3
#undef AREAD
  } else {
    // ---- prologue: A(0),B(0) then A(1),B(1) ----
    gload16(aSrc + pA0,         ldsA + (wid << 10));
    gload16(aSrc + pA1,         ldsA + 4096 + (wid << 10));
    gload16(bSrc + pB,          ldsB + (wid << 10));
    gload16(aSrc + 64 + pA0,    ldsA + 8192 + (wid << 10));
    gload16(aSrc + 64 + pA1,    ldsA + 8192 + 4096 + (wid << 10));
    gload16(bSrc + 32768 + pB,  ldsB + 4096 + (wid << 10));
    VWAIT(3);
    BARRIER;

#define PH1(KC, S) do {                                                                 \
    constexpr int S2 = ((S) + 2) & 3;                                                   \
    const int kcn_ = ((KC) + 2 < 16) ? (KC) + 2 : 15;                                   \
    gload16(bSrc + (size_t)kcn_ * 32768 + pB, ldsB + S2 * 4096 + (wid << 10));          \
    gload16(aSrc + kcn_ * 64 + pA0, ldsA + S2 * 8192 + (wid << 10));                    \
    gload16(aSrc + kcn_ * 64 + pA1, ldsA + S2 * 8192 + 4096 + (wid << 10));             \
    SCHEDB;                                                                             \
    bf8 af0 = *(const bf8*)(ldsA + (S) * 8192 + 0    + aAddr);                          \
    bf8 af1 = *(const bf8*)(ldsA + (S) * 8192 + 1024 + aAddr);                          \
    bf8 af2 = *(const bf8*)(ldsA + (S) * 8192 + 2048 + aAddr);                          \
    bf8 af3 = *(const bf8*)(ldsA + (S) * 8192 + 3072 + aAddr);                          \
    bf8 bq0 = *(const bf8*)(ldsB + (S) * 4096 + 0   + bAddr);                           \
    bf8 bq1 = *(const bf8*)(ldsB + (S) * 4096 + 256 + bAddr);                           \
    __builtin_amdgcn_s_setprio(1);                                                      \
    acc[0][0] = mfma_bf16(af0, bq0, acc[0][0]);                                         \
    acc[0][1] = mfma_bf16(af0, bq1, acc[0][1]);                                         \
    acc[1][0] = mfma_bf16(af1, bq0, acc[1][0]);                                         \
    acc[1][1] = mfma_bf16(af1, bq1, acc[1][1]);                                         \
    acc[2][0] = mfma_bf16(af2, bq0, acc[2][0]);                                         \
    acc[2][1] = mfma_bf16(af2, bq1, acc[2][1]);                                         \
    acc[3][0] = mfma_bf16(af3, bq0, acc[3][0]);                                         \
    acc[3][1] = mfma_bf16(af3, bq1, acc[3][1]);                                         \
    __builtin_amdgcn_s_setprio(0);                                                      \
    VWAIT(3);                                                                           \
    BARRIER;                                                                            \
  } while (0)

    for (int kc4 = 0; kc4 < 4; kc4++) {
      PH1(kc4 * 4 + 0, 0); PH1(kc4 * 4 + 1, 1); PH1(kc4 * 4 + 2, 2); PH1(kc4 * 4 + 3, 3);
    }
#undef PH1
  }

  VWAIT(0);   // drain stray prefetches before LDS teardown

  // ---- epilogue ----
#pragma unroll
  for (int m = 0; m < 4; m++) {
    int pbase = p0 + wv * 64 + m * 16 + lhi * 4;
#pragma unroll
    for (int n = 0; n < 2; n++) {
      int co = co0 + wc * 32 + n * 16 + l15;
      if constexpr (EPI == 7) {
        float bv = bias[co];
#pragma unroll
        for (int r = 0; r < 4; r++)
          o0[((size_t)b * NSP + pbase + r) * CH_ + co] = f2bf(acc[m][n][r] + bv);
      } else if constexpr (EPI == 8) {
        float bv = bias[co];
        float rv = bias2[co];
#pragma unroll
        for (int r = 0; r < 4; r++) {
          size_t idx = ((size_t)b * NSP + pbase + r) * CH_ + co;
          o0[idx]    = f2bf(acc[m][n][r] + bv);
          outf2[idx] = accR[m][n][r] + rv;
        }
      } else if constexpr (EPI == 2) {
        float bv = bias[co];
        f32x4 v;
#pragma unroll
        for (int r = 0; r < 4; r++)
          v[r] = acc[m][n][r] + bv + addf[((size_t)b * NSP + pbase + r) * CH_ + co];
        *(f32x4*)(outf + ((size_t)b * CH_ + co) * NSP + pbase) = v;
      } else {  // EPI == 5 (qkv)
        if (seg == 0) {
          float bv = b0[co];
#pragma unroll
          for (int r = 0; r < 4; r++)
            o0[((size_t)b * NSP + pbase + r) * CH_ + co] = f2bf((acc[m][n][r] + bv) * QSCALE);
        } else if (seg == 1) {
          float bv = b1[co];
#pragma unroll
          for (int r = 0; r < 4; r++)
            o1[((size_t)b * NSP + pbase + r) * CH_ + co] = f2bf(acc[m][n][r] + bv);
        } else {
          float bv = b2[co];
          union { bf4 v; u64 u; } pk4;
#pragma unroll
          for (int r = 0; r < 4; r++) pk4.v[r] = (short)f2bf(acc[m][n][r] + bv);
          int np = (pbase & ~31) | ((pbase & 12) << 1) | ((pbase & 16) >> 2);  // kpos permute
          *(u64*)(o2 + ((size_t)b * CH_ + co) * NSP + np) = pk4.u;
        }
      }
    }
  }
}

// ---------------- GroupNorm (bf16 input, vectorized) ----------------
// MODE 0: y = silu(gn(x))              -> outb (bf16, PADDED NHWC)
// MODE 1: y = gn(x)*(1+cond)+resid     -> outf (f32) + outb (bf16 NHWC)
template <int MODE>
__global__ __launch_bounds__(256) void gn_kernel(
    const u16* __restrict__ in, const float* __restrict__ gw, const float* __restrict__ gb,
    const float* __restrict__ cond, const float* __restrict__ resid,
    float* __restrict__ outf, u16* __restrict__ outb) {
  int b = blockIdx.y, g = blockIdx.x;
  int tid = threadIdx.x;
  const u16* base = in + (size_t)b * NSP * CH_ + g * 8;
  bf8 v[4];
  float s = 0.f, ss = 0.f;
#pragma unroll
  for (int i = 0; i < 4; i++) {
    int p = tid + i * 256;
    v[i] = *(const bf8*)(base + (size_t)p * CH_);
#pragma unroll
    for (int j = 0; j < 8; j++) { float f = b2f((u16)v[i][j]); s += f; ss += f * f; }
  }
  __shared__ float rs[256], rss[256];
  rs[tid] = s; rss[tid] = ss;
  __syncthreads();
  for (int off = 128; off > 0; off >>= 1) {
    if (tid < off) { rs[tid] += rs[tid + off]; rss[tid] += rss[tid + off]; }
    __syncthreads();
  }
  float mean = rs[0] * (1.f / 8192.f);
  float var = rss[0] * (1.f / 8192.f) - mean * mean;
  float inv = rsqrtf(var + 1e-5f);
  float gam[8], bet[8], cm[8];
  *(f32x4*)(gam)     = *(const f32x4*)(gw + g * 8);
  *(f32x4*)(gam + 4) = *(const f32x4*)(gw + g * 8 + 4);
  *(f32x4*)(bet)     = *(const f32x4*)(gb + g * 8);
  *(f32x4*)(bet + 4) = *(const f32x4*)(gb + g * 8 + 4);
  if (MODE == 1) {
    *(f32x4*)(cm)     = *(const f32x4*)(cond + b * CH_ + g * 8);
    *(f32x4*)(cm + 4) = *(const f32x4*)(cond + b * CH_ + g * 8 + 4);
#pragma unroll
    for (int j = 0; j < 8; j++) cm[j] += 1.f;
  }
#pragma unroll
  for (int i = 0; i < 4; i++) {
    int p = tid + i * 256;
    if (MODE == 0) {
      bf8 ov;
#pragma unroll
      for (int j = 0; j < 8; j++) {
        float y = (b2f((u16)v[i][j]) - mean) * inv * gam[j] + bet[j];
        float sg = 1.f / (1.f + __expf(-y));
        ov[j] = (short)f2bf(y * sg);
      }
      int yy = p >> 5, xc = p & 31;
      *(bf8*)(outb + ((size_t)b * PPB + (size_t)(yy + 1) * PR + xc + 1) * CH_ + g * 8) = ov;
    } else {
      size_t idx = ((size_t)b * NSP + p) * CH_ + g * 8;
      f32x4 r0 = *(const f32x4*)(resid + idx);
      f32x4 r1 = *(const f32x4*)(resid + idx + 4);
      f32x4 z0, z1; bf8 ov;
#pragma unroll
      for (int j = 0; j < 4; j++) {
        float y = (b2f((u16)v[i][j]) - mean) * inv * gam[j] + bet[j];
        z0[j] = y * cm[j] + r0[j];
        ov[j] = (short)f2bf(z0[j]);
      }
#pragma unroll
      for (int j = 0; j < 4; j++) {
        float y = (b2f((u16)v[i][4 + j]) - mean) * inv * gam[4 + j] + bet[4 + j];
        z1[j] = y * cm[4 + j] + r1[j];
        ov[4 + j] = (short)f2bf(z1[j]);
      }
      *(f32x4*)(outf + idx)     = z0;
      *(f32x4*)(outf + idx + 4) = z1;
      *(bf8*)(outb + idx) = ov;
    }
  }
}

// ---------------- flash attention (2-tile pipeline, no-max exp2 softmax) ----------------
__global__ __launch_bounds__(256, 2) void attn_kernel(const u16* __restrict__ q, const u16* __restrict__ k,
                                                      const u16* __restrict__ vT, u16* __restrict__ ao) {
  int bid = blockIdx.x;
  int swz = (bid & 7) * 64 + (bid >> 3);   // XCD-bijective: each XCD owns one batch
  int b = swz >> 6;
  int head = (swz >> 3) & 7;
  int qt = swz & 7;
  int tid = threadIdx.x, lane = tid & 63, wid = tid >> 6;
  int l15 = lane & 15, lhi = lane >> 4;
  int cb = head * HD;
  int q0 = qt * 128 + wid * 32;

  const char* qp = (const char*)(q + (size_t)b * NSP * CH_ + cb);
  const char* kp = (const char*)(k + (size_t)b * NSP * CH_ + cb);
  const char* vp = (const char*)(vT + ((size_t)b * CH_ + cb) * NSP);

  __shared__ u16 Ksh[3][64 * 64];   // 24 KB
  __shared__ u16 Vsh[3][64 * 64];   // 24 KB

  bf8 aq[2][2];
#pragma unroll
  for (int qh = 0; qh < 2; qh++)
#pragma unroll
    for (int ks = 0; ks < 2; ks++)
      aq[qh][ks] = *(const bf8*)(qp + ((size_t)(q0 + qh * 16 + l15) * CH_ + ks * 32 + lhi * 8) * 2);

  const bf8 ones8 = {16256, 16256, 16256, 16256, 16256, 16256, 16256, 16256};  // bf16 1.0 x8

  f32x4 o[2][4], osum[2];
#pragma unroll
  for (int qh = 0; qh < 2; qh++) {
    osum[qh] = {0.f, 0.f, 0.f, 0.f};
#pragma unroll
    for (int n = 0; n < 4; n++) o[qh][n] = {0.f, 0.f, 0.f, 0.f};
  }

  auto stage = [&](int kt, int buf) {
#pragma unroll
    for (int t = 0; t < 2; t++) {
      int i = wid * 2 + t;
      int chunk = i * 64 + lane;             // 0..511
      int r = chunk >> 3, c = chunk & 7;
      gload16(kp + (size_t)(kt * 64 + r) * 1024 + (size_t)((c ^ (r & 7)) * 16),
              (char*)Ksh[buf] + i * 1024);
    }
#pragma unroll
    for (int t = 0; t < 2; t++) {
      int i = wid * 2 + t;
      int chunk = i * 64 + lane;
      int r = chunk >> 3, c = chunk & 7;     // r = d row of V^T
      gload16(vp + (size_t)r * 2048 + (size_t)(kt * 128) + (size_t)((c ^ (r & 7)) * 16),
              (char*)Vsh[buf] + i * 1024);
    }
  };

  auto qk = [&](int buf, f32x4 (&sacc)[2][4]) {
    const char* Kb = (const char*)Ksh[0] + buf * 8192;
#pragma unroll
    for (int qh = 0; qh < 2; qh++)
#pragma unroll
      for (int kf = 0; kf < 4; kf++) sacc[qh][kf] = {0.f, 0.f, 0.f, 0.f};
#pragma unroll
    for (int kf = 0; kf < 4; kf++) {
      bf8 ak[2];
#pragma unroll
      for (int ks = 0; ks < 2; ks++)
        ak[ks] = *(const bf8*)(Kb + (size_t)(kf * 16 + l15) * 128 + (((ks * 4 + lhi) ^ (l15 & 7)) * 16));
#pragma unroll
      for (int qh = 0; qh < 2; qh++)
#pragma unroll
        for (int ks = 0; ks < 2; ks++)
          sacc[qh][kf] = mfma_bf16(ak[ks], aq[qh][ks], sacc[qh][kf]);
    }
  };

  auto smpv = [&](int buf, f32x4 (&sacc)[2][4]) {
    const char* Vb = (const char*)Vsh[0] + buf * 8192;
    unsigned pk[2][4][2];
#pragma unroll
    for (int qh = 0; qh < 2; qh++)
#pragma unroll
      for (int kf = 0; kf < 4; kf++) {
        f32x4 pv;
#pragma unroll
        for (int r = 0; r < 4; r++) pv[r] = exp2f(sacc[qh][kf][r]);
        pk[qh][kf][0] = cvt_pk_bf16(pv[0], pv[1]);
        pk[qh][kf][1] = cvt_pk_bf16(pv[2], pv[3]);
      }
#pragma unroll
    for (int g = 0; g < 2; g++) {
      union { bf8 v8; unsigned u[4]; } ap[2];
#pragma unroll
      for (int qh = 0; qh < 2; qh++) {
        ap[qh].u[0] = pk[qh][2 * g][0];
        ap[qh].u[1] = pk[qh][2 * g][1];
        ap[qh].u[2] = pk[qh][2 * g + 1][0];
        ap[qh].u[3] = pk[qh][2 * g + 1][1];
      }
#pragma unroll
      for (int nf2 = 0; nf2 < 4; nf2++) {
        int row = nf2 * 16 + l15;
        bf8 bv8 = *(const bf8*)(Vb + (size_t)row * 128 + (((4 * g + lhi) ^ (l15 & 7)) * 16));
#pragma unroll
        for (int qh = 0; qh < 2; qh++)
          o[qh][nf2] = mfma_bf16(ap[qh].v8, bv8, o[qh][nf2]);
      }
#pragma unroll
      for (int qh = 0; qh < 2; qh++)
        osum[qh] = mfma_bf16(ap[qh].v8, ones8, osum[qh]);   // row sums of P
    }
  };

  stage(0, 0);
  stage(1, 1);
  VWAIT(4);        // stage(0) complete; stage(1) may remain in flight
  BARRIER;

  f32x4 saccA[2][4], saccB[2][4];
  qk(0, saccA);    // tile 0

  int bc = 0;      // buffer holding current tile kt
  for (int kt2 = 0; kt2 < 8; kt2++) {
    {  // even tile kt = 2*kt2
      int kt = 2 * kt2;
      int bn = (bc == 2) ? 0 : bc + 1;
      int bs = (bn == 2) ? 0 : bn + 1;
      VWAIT(0);
      BARRIER;
      qk(bn, saccB);
      if (kt < 14) stage(kt + 2, bs);
      smpv(bc, saccA);
      bc = bn;
    }
    {  // odd tile kt = 2*kt2+1
      int kt = 2 * kt2 + 1;
      if (kt < 15) {
        int bn = (bc == 2) ? 0 : bc + 1;
        int bs = (bn == 2) ? 0 : bn + 1;
        VWAIT(0);
        BARRIER;
        qk(bn, saccA);
        if (kt < 14) stage(kt + 2, bs);
        smpv(bc, saccB);
        bc = bn;
      } else {
        smpv(bc, saccB);
      }
    }
  }

#pragma unroll
  for (int qh = 0; qh < 2; qh++) {
    float linv[4];
#pragma unroll
    for (int r = 0; r < 4; r++) linv[r] = 1.f / osum[qh][r];
#pragma unroll
    for (int nf2 = 0; nf2 < 4; nf2++)
#pragma unroll
      for (int r = 0; r < 4; r++) {
        float val = o[qh][nf2][r] * linv[r];
        ao[((size_t)b * NSP + q0 + qh * 16 + lhi * 4 + r) * CH_ + cb + nf2 * 16 + l15] = f2bf(val);
      }
  }
}

// ---------------- launch ----------------

extern "C" void kernel_launch(void* const* d_in, const int* in_sizes, int n_in,
                              void* d_out, int out_size, void* d_ws, size_t ws_size,
                              hipStream_t stream) {
  const float* x    = (const float*)d_in[0];
  const float* cnd  = (const float*)d_in[1];
  const float* c1w  = (const float*)d_in[2];
  const float* c1b  = (const float*)d_in[3];
  const float* g1w  = (const float*)d_in[4];
  const float* g1b  = (const float*)d_in[5];
  const float* c2w  = (const float*)d_in[6];
  const float* c2b  = (const float*)d_in[7];
  const float* g2w  = (const float*)d_in[8];
  const float* g2b  = (const float*)d_in[9];
  const float* cpw  = (const float*)d_in[10];
  const float* cpb  = (const float*)d_in[11];
  const float* rpw  = (const float*)d_in[12];
  const float* rpb  = (const float*)d_in[13];
  const float* qw   = (const float*)d_in[14];
  const float* qb   = (const float*)d_in[15];
  const float* kw   = (const float*)d_in[16];
  const float* kb   = (const float*)d_in[17];
  const float* vw   = (const float*)d_in[18];
  const float* vb   = (const float*)d_in[19];
  const float* ow   = (const float*)d_in[20];
  const float* ob   = (const float*)d_in[21];
  float* out = (float*)d_out;

  char* ws = (char*)d_ws;
  size_t off = 0;
  auto alloc = [&](size_t bytes) -> char* {
    char* p = ws + off;
    off = (off + bytes + 255) & ~(size_t)255;
    return p;
  };
  const size_t ACT_F = (size_t)NB * NSP * CH_ * 4;   // 16 MB
  const size_t ACT_B = (size_t)NB * NSP * CH_ * 2;   // 8 MB
  const size_t PAD_B = (size_t)NB * PPB * CH_ * 2;   // 9.47 MB

  u16* xp    = (u16*)alloc(PAD_B);               // x padded NHWC bf16
  u16* h1p   = (u16*)alloc(PAD_B);               // silu(gn1) padded bf16
  u16* w1p   = (u16*)alloc((size_t)9 * CH_ * CH_ * 2);
  u16* w2p   = (u16*)alloc((size_t)9 * CH_ * CH_ * 2);
  u16* wrp   = (u16*)alloc((size_t)CH_ * CH_ * 2);
  u16* wqkv  = (u16*)alloc((size_t)3 * CH_ * CH_ * 2);
  u16* wop   = (u16*)alloc((size_t)CH_ * CH_ * 2);
  float* cndv = (float*)alloc((size_t)NB * CH_ * 4);
  float* resid = (float*)alloc(ACT_F);           // residual f32 NHWC
  float* h12  = (float*)alloc(ACT_F);            // h f32 (gn2 out, addf input)
  u16* hb    = (u16*)alloc(ACT_B);               // h bf16 (attn input)
  u16* qbuf  = (u16*)alloc(ACT_B);               // Q (pre-scaled, exp2 domain) NHWC bf16
  u16* kbuf  = (u16*)alloc(ACT_B);               // K NHWC bf16
  u16* vTb   = (u16*)alloc(ACT_B);               // V^T [B][512][1024] bf16, kpos-permuted
  u16* aob   = (u16*)alloc(ACT_B);               // conv bf16 activations (actb); later attn out
  if (off > ws_size) return;

  u16* actb = aob;   // conv1/conv2 bf16 out, consumed by gn before attn reuses aob

  // merged prologue (pack_x + border_zero + pack_w3 x2 + pack_w1 x5 + cond)
  prep_kernel<<<8328, 256, 0, stream>>>(x, xp, h1p, c1w, c2w, w1p, w2p,
                                        rpw, qw, kw, vw, ow,
                                        wrp, wqkv, wqkv + (size_t)CH_ * CH_,
                                        wqkv + (size_t)2 * CH_ * CH_, wop,
                                        cnd, cpw, cpb, cndv);

  dim3 ggrid(NSP / 128, CH_ / 64, NB);
  dim3 qgrid(NSP / 128, 3 * CH_ / 64, NB);
  // conv1 (3x3, bf16 out) + FUSED residual proj -> actb bf16, resid f32
  conv_kernel<9, 1, 8><<<ggrid, 256, 0, stream>>>(xp, w1p, c1b, nullptr, nullptr,
                                                  actb, nullptr, nullptr, nullptr, nullptr, nullptr,
                                                  wrp, resid, rpb);
  // gn1 + silu -> h1p (padded bf16)
  gn_kernel<0><<<dim3(NGROUP, NB), 256, 0, stream>>>(actb, g1w, g1b, nullptr, nullptr, nullptr, h1p);
  // conv2 (3x3) -> actb bf16
  conv_kernel<9, 1, 7><<<ggrid, 256, 0, stream>>>(h1p, w2p, c2b, nullptr, nullptr,
                                                  actb, nullptr, nullptr, nullptr, nullptr, nullptr,
                                                  nullptr, nullptr, nullptr);
  // gn2 * (1+cond) + resid -> h12 f32, hb bf16
  gn_kernel<1><<<dim3(NGROUP, NB), 256, 0, stream>>>(actb, g2w, g2b, cndv, resid, h12, hb);
  // fused q/k/vT (1x1)
  conv_kernel<1, 0, 5><<<qgrid, 256, 0, stream>>>(hb, wqkv, nullptr, nullptr, nullptr,
                                                  qbuf, kbuf, vTb, qb, kb, vb,
                                                  nullptr, nullptr, nullptr);
  // attention -> aob bf16 NHWC (actb fully consumed by gn2 already)
  attn_kernel<<<512, 256, 0, stream>>>(qbuf, kbuf, vTb, aob);
  // out proj + bias + h -> d_out NCHW f32 directly
  conv_kernel<1, 0, 2><<<ggrid, 256, 0, stream>>>(aob, wop, ob, out, h12,
                                                  nullptr, nullptr, nullptr, nullptr, nullptr, nullptr,
                                                  nullptr, nullptr, nullptr);
}

// Round 14
// 221.025 us; speedup vs baseline: 1.0820x; 1.0014x over previous
//
#include <hip/hip_runtime.h>
#include <hip/hip_bf16.h>

typedef unsigned short u16;
typedef unsigned long long u64;
typedef __attribute__((ext_vector_type(8))) short bf8;   // 8 bf16 (raw bits, 4 VGPRs)
typedef __attribute__((ext_vector_type(4))) short bf4;   // 4 bf16 (2 VGPRs)
typedef __attribute__((ext_vector_type(4))) float f32x4;

#define CH_ 512
#define NSP 1024      // 32*32 spatial
#define NB 8
#define CONDDIM 1280
#define NGROUP 64     // 512/8
#define HEADS_ 8
#define HD 64         // head dim
#define PR 34         // padded row length (32 + 2)
#define PPB (PR*PR)   // padded positions per batch = 1156
#define QSCALE 0.18033688011112042f   // 0.125 * log2(e): softmax in exp2 domain

#define VWAIT(N) asm volatile("s_waitcnt vmcnt(" #N ")" ::: "memory")
#define SCHEDB __builtin_amdgcn_sched_barrier(0)
#define BARRIER do { SCHEDB; __builtin_amdgcn_s_barrier(); SCHEDB; } while (0)

__device__ __forceinline__ u16 f2bf(float f) {
  union { float f; unsigned u; } v; v.f = f;
  unsigned u = v.u;
  return (u16)((u + 0x7fffu + ((u >> 16) & 1u)) >> 16);   // RNE
}

__device__ __forceinline__ float b2f(u16 x) {
  union { unsigned u; float f; } v; v.u = ((unsigned)x) << 16; return v.f;
}

__device__ __forceinline__ unsigned cvt_pk_bf16(float lo, float hi) {
  unsigned r;
  asm volatile("v_cvt_pk_bf16_f32 %0, %1, %2" : "=v"(r) : "v"(lo), "v"(hi));
  return r;
}

__device__ __forceinline__ f32x4 mfma_bf16(bf8 a, bf8 b, f32x4 c) {
  return __builtin_amdgcn_mfma_f32_16x16x32_bf16(a, b, c, 0, 0, 0);
}

__device__ __forceinline__ void gload16(const void* g, void* l) {
  __builtin_amdgcn_global_load_lds((const __attribute__((address_space(1))) void*)g,
                                   (__attribute__((address_space(3))) void*)l, 16, 0, 0);
}

// ---------------- merged prologue kernel ----------------
// blockIdx ranges (256 threads each):
//   [0,4096)      pack_x: NCHW f32 -> padded NHWC bf16 (interior)
//   [4096,4360)   border zero xp & h1p         (264*256 == 8*132*64 exactly)
//   [4360,6664)   pack both 3x3 weights        (2*1152*256 == 2*9*64*512)
//   [6664,7304)   pack five 1x1 weights        (5*128*256 == 5*64*512)
//   [7304,8328)   cond GEMV                    (8*128 blocks)
__global__ __launch_bounds__(256) void prep_kernel(
    const float* __restrict__ x, u16* __restrict__ xp, u16* __restrict__ h1p,
    const float* __restrict__ c1w, const float* __restrict__ c2w,
    u16* __restrict__ w1p, u16* __restrict__ w2p,
    const float* __restrict__ rpw, const float* __restrict__ qw, const float* __restrict__ kw,
    const float* __restrict__ vw, const float* __restrict__ ow,
    u16* __restrict__ wrp, u16* __restrict__ wq, u16* __restrict__ wk,
    u16* __restrict__ wv, u16* __restrict__ wo,
    const float* __restrict__ cd, const float* __restrict__ cpw,
    const float* __restrict__ cpb, float* __restrict__ cond) {
  __shared__ float t[32][33];
  int bid = blockIdx.x;
  int tid = threadIdx.x;
  if (bid < 4096) {
    int px = bid & 31, py = (bid >> 5) & 15, b = bid >> 9;
    int c0 = py * 32, p0 = px * 32;
    int tx = tid & 31, ty = tid >> 5;
#pragma unroll
    for (int i = 0; i < 4; i++) {
      int row = ty + i * 8;
      t[row][tx] = x[((size_t)b * CH_ + c0 + row) * NSP + p0 + tx];
    }
    __syncthreads();
#pragma unroll
    for (int i = 0; i < 4; i++) {
      int pr = ty + i * 8;
      int p = p0 + pr;
      int y = p >> 5, xc = p & 31;
      xp[((size_t)b * PPB + (size_t)(y + 1) * PR + xc + 1) * CH_ + c0 + tx] = f2bf(t[tx][pr]);
    }
  } else if (bid < 4360) {
    int id = (bid - 4096) * 256 + tid;      // < 67584 == NB*132*64 exactly
    int ch8 = id & 63;
    int rest = id >> 6;
    int bidx = rest % 132;
    int bb = rest / 132;
    int r, c;
    if (bidx < 34)       { r = 0;          c = bidx; }
    else if (bidx < 68)  { r = 33;         c = bidx - 34; }
    else if (bidx < 100) { r = bidx - 67;  c = 0; }
    else                 { r = bidx - 99;  c = 33; }
    size_t off = ((size_t)bb * PPB + (size_t)r * PR + c) * CH_ + ch8 * 8;
    const bf8 z = {0, 0, 0, 0, 0, 0, 0, 0};
    *(bf8*)(xp + off) = z;
    *(bf8*)(h1p + off) = z;
  } else if (bid < 6664) {
    int id2 = bid - 4360;
    int which = (id2 >= 1152) ? 1 : 0;
    int id = (id2 - which * 1152) * 256 + tid;   // < 294912 == 9*64*512 exactly
    const float* w = which ? c2w : c1w;
    u16* wp = which ? w2p : w1p;
    int co = id & (CH_ - 1);
    int cib = (id >> 9) & 63;
    int tt = id >> 15;
    int dy = tt / 3, dx = tt % 3;
    bf8 v;
#pragma unroll
    for (int j = 0; j < 8; j++) {
      int ci = cib * 8 + j;
      v[j] = (short)f2bf(w[(((size_t)co * CH_ + ci) * 3 + dy) * 3 + dx]);
    }
    *(bf8*)(wp + ((size_t)(tt * 64 + cib) * CH_ + co) * 8) = v;
  } else if (bid < 7304) {
    int id3 = bid - 6664;
    int which = id3 >> 7;                   // 0..4
    int id = (id3 & 127) * 256 + tid;       // < 32768 == 64*512 exactly
    const float* w; u16* wp;
    switch (which) {
      case 0: w = rpw; wp = wrp; break;
      case 1: w = qw;  wp = wq;  break;
      case 2: w = kw;  wp = wk;  break;
      case 3: w = vw;  wp = wv;  break;
      default: w = ow; wp = wo;  break;
    }
    int co = id & (CH_ - 1);
    int cib = id >> 9;
    bf8 v;
#pragma unroll
    for (int j = 0; j < 8; j++) v[j] = (short)f2bf(w[(size_t)co * CH_ + cib * 8 + j]);
    *(bf8*)(wp + ((size_t)cib * CH_ + co) * 8) = v;
  } else {
    int id4 = bid - 7304;
    int b = id4 >> 7;
    int c = (id4 & 127) * 4 + (tid >> 6);
    int lane = tid & 63;
    const float* wrow = cpw + (size_t)c * CONDDIM;
    const float* crow = cd + (size_t)b * CONDDIM;
    float s = 0.f;
    for (int i = lane; i < CONDDIM; i += 64) s += crow[i] * wrow[i];
#pragma unroll
    for (int m = 32; m > 0; m >>= 1) s += __shfl_xor(s, m, 64);
    if (lane == 0) cond[b * CH_ + c] = s + cpb[c];
  }
}

// ---------------- counted-vmcnt implicit-GEMM conv ----------------
// A-tile LDS chunk XOR swizzle (c' = lhi ^ ((row>>1)&3)), both-sides (rule #21).
// 3x3: 3 taps/phase; B = TWO 12KB halves staged ONE phase ahead (r9-validated
//   waits: T0 vmcnt(2), T1 vmcnt(1) (+R: 2), T2 vmcnt(1)). conv2 LDS 52KB -> 3 blk/CU.
// 1x1: THREE slots (A 24KB + B 12KB = 36KB -> 4 blk/CU), 2-phase-ahead, vmcnt(3).
// EPI: 2 = FINAL f32 NCHW vectorized (+bias+addf NHWC);
//      5 = QKV fused (seg: q bf16*QSCALE / k bf16 / vT bf16 KPOS-PERMUTED);
//      7 = bf16 NHWC out (+bias)                        [conv2]
//      8 = conv1: bf16 NHWC out + FUSED residual 1x1 (center tap, wp2/bias2 -> outf2 f32)
template <int TAPS, int PIN, int EPI>
__global__ __launch_bounds__(256, TAPS == 9 ? 3 : 4) void conv_kernel(
    const u16* __restrict__ in, const u16* __restrict__ wp, const float* __restrict__ bias,
    float* __restrict__ outf, const float* __restrict__ addf,
    u16* __restrict__ o0, u16* __restrict__ o1, u16* __restrict__ o2,
    const float* __restrict__ b0, const float* __restrict__ b1, const float* __restrict__ b2,
    const u16* __restrict__ wp2, float* __restrict__ outf2, const float* __restrict__ bias2) {
  constexpr int LDSZ = (TAPS == 9) ? (2 * 14336 + 2 * 12288 + (EPI == 8 ? 2 * 4096 : 0))
                                   : (3 * 8192 + 3 * 4096);
  __shared__ char lds[LDSZ];
  char* ldsA = lds;
  char* ldsB = lds + ((TAPS == 9) ? 2 * 14336 : 3 * 8192);
  char* ldsR = lds + 2 * 14336 + 2 * 12288;   // only used when EPI==8

  const int b = blockIdx.z;
  int seg = 0, coy = blockIdx.y;
  if constexpr (EPI == 5) { seg = coy >> 3; coy &= 7; }
  const int co0 = coy * 64;
  const int p0 = blockIdx.x * 128;
  const int tid = threadIdx.x;
  const int lane = tid & 63, wid = tid >> 6;
  const int wv = wid >> 1, wc = wid & 1;
  const int l15 = lane & 15, lhi = lane >> 4;

  // global bases
  const char* aSrc;
  if constexpr (TAPS == 9) {
    aSrc = (const char*)in + ((size_t)b * PPB + (size_t)blockIdx.x * 4 * PR) * 1024;
  } else if constexpr (PIN) {
    aSrc = (const char*)in + (size_t)b * PPB * 1024;
  } else {
    aSrc = (const char*)in + ((size_t)b * NSP + p0) * 1024;
  }
  const char* bSrc = (const char*)wp + (size_t)((EPI == 5) ? seg * 524288 : 0) + co0 * 16;
  const char* rSrc = (const char*)wp2 + co0 * 16;   // EPI==8 only

  // per-thread staging source offsets (chunk pre-swizzled: c_src = (tid&3) ^ ((row>>1)&3))
  const int pB = ((tid >> 6) * 512 + (tid & 63)) * 16;
  int pA0, pA1, pA3 = 0;
  if constexpr (TAPS == 9) {
    int r0 = tid >> 2;
    int c0s = (tid & 3) ^ ((r0 >> 1) & 3);
    pA0 = (r0 << 10) + (c0s << 4);
    int r3 = 192 + ((tid & 127) >> 2);
    int c3s = (tid & 3) ^ ((r3 >> 1) & 3);
    pA3 = (r3 << 10) + (c3s << 4);
    pA1 = 0;
  } else {
    int a0 = (tid >> 2), a1 = 64 + (tid >> 2);
    int cs = (tid & 3) ^ (((tid >> 2) >> 1) & 3);
    if constexpr (PIN) {
      int pp0 = p0 + a0, pp1 = p0 + a1;
      int g0 = ((pp0 >> 5) + 1) * PR + (pp0 & 31) + 1;
      int g1 = ((pp1 >> 5) + 1) * PR + (pp1 & 31) + 1;
      pA0 = (g0 << 10) + (cs << 4);
      pA1 = (g1 << 10) + (cs << 4);
    } else {
      pA0 = (a0 << 10) + (cs << 4);
      pA1 = (a1 << 10) + (cs << 4);
    }
  }

  // per-thread LDS read bases
  const int rowbA = (TAPS == 9) ? (wv * 68 + l15) : (wv * 64 + l15);
  const int aAddr = rowbA * 64 + ((lhi ^ ((l15 >> 1) & 3)) << 4);      // 1x1 path only
  const int bAddr = (lhi * 64 + wc * 32 + l15) * 16;

  f32x4 acc[4][2], accR[4][2];
#pragma unroll
  for (int m = 0; m < 4; m++)
#pragma unroll
    for (int n = 0; n < 2; n++) { acc[m][n] = {0.f, 0.f, 0.f, 0.f}; accR[m][n] = {0.f, 0.f, 0.f, 0.f}; }

  if constexpr (TAPS == 9) {
    // ---- prologue: A(kc0) fully + B taps 0-2 (kc0) -> half 0 [+ R(kc0)] ----
    gload16(aSrc + pA0,          ldsA + (wid << 10));
    gload16(aSrc + pA0 + 65536,  ldsA + 4096 + (wid << 10));
    gload16(aSrc + pA0 + 131072, ldsA + 8192 + (wid << 10));
    gload16(aSrc + pA3,          ldsA + 12288 + ((wid & 1) << 10));
    gload16(bSrc + (size_t)(0 * 64) * 8192 + pB, ldsB + (wid << 10));
    gload16(bSrc + (size_t)(1 * 64) * 8192 + pB, ldsB + 4096 + (wid << 10));
    gload16(bSrc + (size_t)(2 * 64) * 8192 + pB, ldsB + 8192 + (wid << 10));
    if constexpr (EPI == 8) gload16(rSrc + pB, ldsR + (wid << 10));
    VWAIT(0);
    BARRIER;

// swizzled A fragment read: row = rowbA + K (K compile-time per fragment)
#define AREAD(Ab_, K) (*(const bf8*)((Ab_) + (rowbA + (K)) * 64 + ((lhi ^ (((rowbA + (K)) >> 1) & 3)) << 4)))

// phase (KC, T): consumes B half H, A buf AS; stages NEXT phase's 3 B tiles
// into half 1-H; A(kc+1) spread T0(2)/T1(1)/T2(1); R(kc+1) at T1.
#define PH3(KC, T, AS, H) do {                                                          \
    const int kcn_ = ((KC) < 15) ? (KC) + 1 : 15;                                       \
    { const int kb_ = ((T) == 2) ? kcn_ : (KC);                                         \
      const int tn_ = 3 * (((T) + 1) % 3);                                              \
      gload16(bSrc + (size_t)((tn_ + 0) * 64 + kb_ * 4) * 8192 + pB,                    \
              ldsB + (1 - (H)) * 12288 + (wid << 10));                                  \
      gload16(bSrc + (size_t)((tn_ + 1) * 64 + kb_ * 4) * 8192 + pB,                    \
              ldsB + (1 - (H)) * 12288 + 4096 + (wid << 10));                           \
      gload16(bSrc + (size_t)((tn_ + 2) * 64 + kb_ * 4) * 8192 + pB,                    \
              ldsB + (1 - (H)) * 12288 + 8192 + (wid << 10)); }                         \
    if constexpr ((T) == 0) {                                                           \
      gload16(aSrc + kcn_ * 64 + pA0,         ldsA + (1 - (AS)) * 14336 + (wid << 10)); \
      gload16(aSrc + kcn_ * 64 + pA0 + 65536, ldsA + (1 - (AS)) * 14336 + 4096 + (wid << 10)); \
    } else if constexpr ((T) == 1) {                                                    \
      gload16(aSrc + kcn_ * 64 + pA0 + 131072, ldsA + (1 - (AS)) * 14336 + 8192 + (wid << 10)); \
      if constexpr (EPI == 8)                                                           \
        if ((KC) < 15)                                                                  \
          gload16(rSrc + (size_t)kcn_ * 32768 + pB, ldsR + (kcn_ & 1) * 4096 + (wid << 10)); \
    } else {                                                                            \
      gload16(aSrc + kcn_ * 64 + pA3, ldsA + (1 - (AS)) * 14336 + 12288 + ((wid & 1) << 10)); \
    }                                                                                   \
    SCHEDB;                                                                             \
    {                                                                                   \
      const char* Ab_ = ldsA + (AS) * 14336;                                            \
      const char* Bb_ = ldsB + (H) * 12288;                                             \
      bf8 af_[3][4], bq_[3][2];                                                         \
      _Pragma("unroll")                                                                 \
      for (int tt = 0; tt < 3; tt++) {                                                  \
        const int DT_ = (T) * 34 + tt;                                                  \
        af_[tt][0] = AREAD(Ab_, DT_ + 0);                                               \
        af_[tt][1] = AREAD(Ab_, DT_ + 16);                                              \
        af_[tt][2] = AREAD(Ab_, DT_ + 34);                                              \
        af_[tt][3] = AREAD(Ab_, DT_ + 50);                                              \
        bq_[tt][0] = *(const bf8*)(Bb_ + tt * 4096 + 0   + bAddr);                      \
        bq_[tt][1] = *(const bf8*)(Bb_ + tt * 4096 + 256 + bAddr);                      \
      }                                                                                 \
      __builtin_amdgcn_s_setprio(1);                                                    \
      _Pragma("unroll")                                                                 \
      for (int tt = 0; tt < 3; tt++)                                                    \
        _Pragma("unroll")                                                               \
        for (int m = 0; m < 4; m++) {                                                   \
          acc[m][0] = mfma_bf16(af_[tt][m], bq_[tt][0], acc[m][0]);                     \
          acc[m][1] = mfma_bf16(af_[tt][m], bq_[tt][1], acc[m][1]);                     \
        }                                                                               \
      if constexpr (EPI == 8 && (T) == 1) {                                             \
        bf8 rq0 = *(const bf8*)(ldsR + ((KC) & 1) * 4096 + 0   + bAddr);                \
        bf8 rq1 = *(const bf8*)(ldsR + ((KC) & 1) * 4096 + 256 + bAddr);                \
        _Pragma("unroll")                                                               \
        for (int m = 0; m < 4; m++) {                                                   \
          accR[m][0] = mfma_bf16(af_[1][m], rq0, accR[m][0]);                           \
          accR[m][1] = mfma_bf16(af_[1][m], rq1, accR[m][1]);                           \
        }                                                                               \
      }                                                                                 \
      __builtin_amdgcn_s_setprio(0);                                                    \
    }                                                                                   \
    if constexpr ((T) == 0) { VWAIT(2); }                                               \
    else if constexpr ((T) == 1) {                                                      \
      if constexpr (EPI == 8) { VWAIT(2); } else { VWAIT(1); }                          \
    } else { VWAIT(1); }                                                                \
    BARRIER;                                                                            \
  } while (0)

    for (int kc2 = 0; kc2 < 8; kc2++) {
      PH3(kc2 * 2,     0, 0, 0); PH3(kc2 * 2,     1, 0, 1); PH3(kc2 * 2,     2, 0, 0);
      PH3(kc2 * 2 + 1, 0, 1, 1); PH3(kc2 * 2 + 1, 1, 1, 0); PH3(kc2 * 2 + 1, 2, 1, 1);
    }
#undef PH3
#undef AREAD
  } else {
    // ---- prologue: A(0),B(0) -> slot0; A(1),B(1) -> slot1 ----
    gload16(aSrc + pA0,         ldsA + (wid << 10));
    gload16(aSrc + pA1,         ldsA + 4096 + (wid << 10));
    gload16(bSrc + pB,          ldsB + (wid << 10));
    gload16(aSrc + 64 + pA0,    ldsA + 8192 + (wid << 10));
    gload16(aSrc + 64 + pA1,    ldsA + 8192 + 4096 + (wid << 10));
    gload16(bSrc + 32768 + pB,  ldsB + 4096 + (wid << 10));
    VWAIT(3);
    BARRIER;

// 3-slot rotation: phase KC consumes slot S=KC%3, stages KC+2 into (S+2)%3.
#define PH1(KC, S) do {                                                                 \
    constexpr int S2 = ((S) + 2) % 3;                                                   \
    const int kcn_ = ((KC) + 2 < 16) ? (KC) + 2 : 15;                                   \
    gload16(bSrc + (size_t)kcn_ * 32768 + pB, ldsB + S2 * 4096 + (wid << 10));          \
    gload16(aSrc + kcn_ * 64 + pA0, ldsA + S2 * 8192 + (wid << 10));                    \
    gload16(aSrc + kcn_ * 64 + pA1, ldsA + S2 * 8192 + 4096 + (wid << 10));             \
    SCHEDB;                                                                             \
    bf8 af0 = *(const bf8*)(ldsA + (S) * 8192 + 0    + aAddr);                          \
    bf8 af1 = *(const bf8*)(ldsA + (S) * 8192 + 1024 + aAddr);                          \
    bf8 af2 = *(const bf8*)(ldsA + (S) * 8192 + 2048 + aAddr);                          \
    bf8 af3 = *(const bf8*)(ldsA + (S) * 8192 + 3072 + aAddr);                          \
    bf8 bq0 = *(const bf8*)(ldsB + (S) * 4096 + 0   + bAddr);                           \
    bf8 bq1 = *(const bf8*)(ldsB + (S) * 4096 + 256 + bAddr);                           \
    __builtin_amdgcn_s_setprio(1);                                                      \
    acc[0][0] = mfma_bf16(af0, bq0, acc[0][0]);                                         \
    acc[0][1] = mfma_bf16(af0, bq1, acc[0][1]);                                         \
    acc[1][0] = mfma_bf16(af1, bq0, acc[1][0]);                                         \
    acc[1][1] = mfma_bf16(af1, bq1, acc[1][1]);                                         \
    acc[2][0] = mfma_bf16(af2, bq0, acc[2][0]);                                         \
    acc[2][1] = mfma_bf16(af2, bq1, acc[2][1]);                                         \
    acc[3][0] = mfma_bf16(af3, bq0, acc[3][0]);                                         \
    acc[3][1] = mfma_bf16(af3, bq1, acc[3][1]);                                         \
    __builtin_amdgcn_s_setprio(0);                                                      \
    VWAIT(3);                                                                           \
    BARRIER;                                                                            \
  } while (0)

    PH1(0, 0);  PH1(1, 1);  PH1(2, 2);  PH1(3, 0);
    PH1(4, 1);  PH1(5, 2);  PH1(6, 0);  PH1(7, 1);
    PH1(8, 2);  PH1(9, 0);  PH1(10, 1); PH1(11, 2);
    PH1(12, 0); PH1(13, 1); PH1(14, 2); PH1(15, 0);
#undef PH1
  }

  VWAIT(0);   // drain stray prefetches before LDS teardown

  // ---- epilogue ----
#pragma unroll
  for (int m = 0; m < 4; m++) {
    int pbase = p0 + wv * 64 + m * 16 + lhi * 4;
#pragma unroll
    for (int n = 0; n < 2; n++) {
      int co = co0 + wc * 32 + n * 16 + l15;
      if constexpr (EPI == 7) {
        float bv = bias[co];
#pragma unroll
        for (int r = 0; r < 4; r++)
          o0[((size_t)b * NSP + pbase + r) * CH_ + co] = f2bf(acc[m][n][r] + bv);
      } else if constexpr (EPI == 8) {
        float bv = bias[co];
        float rv = bias2[co];
#pragma unroll
        for (int r = 0; r < 4; r++) {
          size_t idx = ((size_t)b * NSP + pbase + r) * CH_ + co;
          o0[idx]    = f2bf(acc[m][n][r] + bv);
          outf2[idx] = accR[m][n][r] + rv;
        }
      } else if constexpr (EPI == 2) {
        float bv = bias[co];
        f32x4 v;
#pragma unroll
        for (int r = 0; r < 4; r++)
          v[r] = acc[m][n][r] + bv + addf[((size_t)b * NSP + pbase + r) * CH_ + co];
        *(f32x4*)(outf + ((size_t)b * CH_ + co) * NSP + pbase) = v;
      } else {  // EPI == 5 (qkv)
        if (seg == 0) {
          float bv = b0[co];
#pragma unroll
          for (int r = 0; r < 4; r++)
            o0[((size_t)b * NSP + pbase + r) * CH_ + co] = f2bf((acc[m][n][r] + bv) * QSCALE);
        } else if (seg == 1) {
          float bv = b1[co];
#pragma unroll
          for (int r = 0; r < 4; r++)
            o1[((size_t)b * NSP + pbase + r) * CH_ + co] = f2bf(acc[m][n][r] + bv);
        } else {
          float bv = b2[co];
          union { bf4 v; u64 u; } pk4;
#pragma unroll
          for (int r = 0; r < 4; r++) pk4.v[r] = (short)f2bf(acc[m][n][r] + bv);
          int np = (pbase & ~31) | ((pbase & 12) << 1) | ((pbase & 16) >> 2);  // kpos permute
          *(u64*)(o2 + ((size_t)b * CH_ + co) * NSP + np) = pk4.u;
        }
      }
    }
  }
}

// ---------------- GroupNorm (bf16 input, vectorized) ----------------
// MODE 0: y = silu(gn(x))              -> outb (bf16, PADDED NHWC)
// MODE 1: y = gn(x)*(1+cond)+resid     -> outf (f32) + outb (bf16 NHWC)
template <int MODE>
__global__ __launch_bounds__(256) void gn_kernel(
    const u16* __restrict__ in, const float* __restrict__ gw, const float* __restrict__ gb,
    const float* __restrict__ cond, const float* __restrict__ resid,
    float* __restrict__ outf, u16* __restrict__ outb) {
  int b = blockIdx.y, g = blockIdx.x;
  int tid = threadIdx.x;
  const u16* base = in + (size_t)b * NSP * CH_ + g * 8;
  bf8 v[4];
  float s = 0.f, ss = 0.f;
#pragma unroll
  for (int i = 0; i < 4; i++) {
    int p = tid + i * 256;
    v[i] = *(const bf8*)(base + (size_t)p * CH_);
#pragma unroll
    for (int j = 0; j < 8; j++) { float f = b2f((u16)v[i][j]); s += f; ss += f * f; }
  }
  __shared__ float rs[256], rss[256];
  rs[tid] = s; rss[tid] = ss;
  __syncthreads();
  for (int off = 128; off > 0; off >>= 1) {
    if (tid < off) { rs[tid] += rs[tid + off]; rss[tid] += rss[tid + off]; }
    __syncthreads();
  }
  float mean = rs[0] * (1.f / 8192.f);
  float var = rss[0] * (1.f / 8192.f) - mean * mean;
  float inv = rsqrtf(var + 1e-5f);
  float gam[8], bet[8], cm[8];
  *(f32x4*)(gam)     = *(const f32x4*)(gw + g * 8);
  *(f32x4*)(gam + 4) = *(const f32x4*)(gw + g * 8 + 4);
  *(f32x4*)(bet)     = *(const f32x4*)(gb + g * 8);
  *(f32x4*)(bet + 4) = *(const f32x4*)(gb + g * 8 + 4);
  if (MODE == 1) {
    *(f32x4*)(cm)     = *(const f32x4*)(cond + b * CH_ + g * 8);
    *(f32x4*)(cm + 4) = *(const f32x4*)(cond + b * CH_ + g * 8 + 4);
#pragma unroll
    for (int j = 0; j < 8; j++) cm[j] += 1.f;
  }
#pragma unroll
  for (int i = 0; i < 4; i++) {
    int p = tid + i * 256;
    if (MODE == 0) {
      bf8 ov;
#pragma unroll
      for (int j = 0; j < 8; j++) {
        float y = (b2f((u16)v[i][j]) - mean) * inv * gam[j] + bet[j];
        float sg = 1.f / (1.f + __expf(-y));
        ov[j] = (short)f2bf(y * sg);
      }
      int yy = p >> 5, xc = p & 31;
      *(bf8*)(outb + ((size_t)b * PPB + (size_t)(yy + 1) * PR + xc + 1) * CH_ + g * 8) = ov;
    } else {
      size_t idx = ((size_t)b * NSP + p) * CH_ + g * 8;
      f32x4 r0 = *(const f32x4*)(resid + idx);
      f32x4 r1 = *(const f32x4*)(resid + idx + 4);
      f32x4 z0, z1; bf8 ov;
#pragma unroll
      for (int j = 0; j < 4; j++) {
        float y = (b2f((u16)v[i][j]) - mean) * inv * gam[j] + bet[j];
        z0[j] = y * cm[j] + r0[j];
        ov[j] = (short)f2bf(z0[j]);
      }
#pragma unroll
      for (int j = 0; j < 4; j++) {
        float y = (b2f((u16)v[i][4 + j]) - mean) * inv * gam[4 + j] + bet[4 + j];
        z1[j] = y * cm[4 + j] + r1[j];
        ov[4 + j] = (short)f2bf(z1[j]);
      }
      *(f32x4*)(outf + idx)     = z0;
      *(f32x4*)(outf + idx + 4) = z1;
      *(bf8*)(outb + idx) = ov;
    }
  }
}

// ---------------- flash attention (2-tile pipeline, no-max exp2 softmax) ----------------
__global__ __launch_bounds__(256, 2) void attn_kernel(const u16* __restrict__ q, const u16* __restrict__ k,
                                                      const u16* __restrict__ vT, u16* __restrict__ ao) {
  int bid = blockIdx.x;
  int swz = (bid & 7) * 64 + (bid >> 3);   // XCD-bijective: each XCD owns one batch
  int b = swz >> 6;
  int head = (swz >> 3) & 7;
  int qt = swz & 7;
  int tid = threadIdx.x, lane = tid & 63, wid = tid >> 6;
  int l15 = lane & 15, lhi = lane >> 4;
  int cb = head * HD;
  int q0 = qt * 128 + wid * 32;

  const char* qp = (const char*)(q + (size_t)b * NSP * CH_ + cb);
  const char* kp = (const char*)(k + (size_t)b * NSP * CH_ + cb);
  const char* vp = (const char*)(vT + ((size_t)b * CH_ + cb) * NSP);

  __shared__ u16 Ksh[3][64 * 64];   // 24 KB
  __shared__ u16 Vsh[3][64 * 64];   // 24 KB

  bf8 aq[2][2];
#pragma unroll
  for (int qh = 0; qh < 2; qh++)
#pragma unroll
    for (int ks = 0; ks < 2; ks++)
      aq[qh][ks] = *(const bf8*)(qp + ((size_t)(q0 + qh * 16 + l15) * CH_ + ks * 32 + lhi * 8) * 2);

  const bf8 ones8 = {16256, 16256, 16256, 16256, 16256, 16256, 16256, 16256};  // bf16 1.0 x8

  f32x4 o[2][4], osum[2];
#pragma unroll
  for (int qh = 0; qh < 2; qh++) {
    osum[qh] = {0.f, 0.f, 0.f, 0.f};
#pragma unroll
    for (int n = 0; n < 4; n++) o[qh][n] = {0.f, 0.f, 0.f, 0.f};
  }

  auto stage = [&](int kt, int buf) {
#pragma unroll
    for (int t = 0; t < 2; t++) {
      int i = wid * 2 + t;
      int chunk = i * 64 + lane;             // 0..511
      int r = chunk >> 3, c = chunk & 7;
      gload16(kp + (size_t)(kt * 64 + r) * 1024 + (size_t)((c ^ (r & 7)) * 16),
              (char*)Ksh[buf] + i * 1024);
    }
#pragma unroll
    for (int t = 0; t < 2; t++) {
      int i = wid * 2 + t;
      int chunk = i * 64 + lane;
      int r = chunk >> 3, c = chunk & 7;     // r = d row of V^T
      gload16(vp + (size_t)r * 2048 + (size_t)(kt * 128) + (size_t)((c ^ (r & 7)) * 16),
              (char*)Vsh[buf] + i * 1024);
    }
  };

  auto qk = [&](int buf, f32x4 (&sacc)[2][4]) {
    const char* Kb = (const char*)Ksh[0] + buf * 8192;
#pragma unroll
    for (int qh = 0; qh < 2; qh++)
#pragma unroll
      for (int kf = 0; kf < 4; kf++) sacc[qh][kf] = {0.f, 0.f, 0.f, 0.f};
#pragma unroll
    for (int kf = 0; kf < 4; kf++) {
      bf8 ak[2];
#pragma unroll
      for (int ks = 0; ks < 2; ks++)
        ak[ks] = *(const bf8*)(Kb + (size_t)(kf * 16 + l15) * 128 + (((ks * 4 + lhi) ^ (l15 & 7)) * 16));
#pragma unroll
      for (int qh = 0; qh < 2; qh++)
#pragma unroll
        for (int ks = 0; ks < 2; ks++)
          sacc[qh][kf] = mfma_bf16(ak[ks], aq[qh][ks], sacc[qh][kf]);
    }
  };

  auto smpv = [&](int buf, f32x4 (&sacc)[2][4]) {
    const char* Vb = (const char*)Vsh[0] + buf * 8192;
    unsigned pk[2][4][2];
#pragma unroll
    for (int qh = 0; qh < 2; qh++)
#pragma unroll
      for (int kf = 0; kf < 4; kf++) {
        f32x4 pv;
#pragma unroll
        for (int r = 0; r < 4; r++) pv[r] = exp2f(sacc[qh][kf][r]);
        pk[qh][kf][0] = cvt_pk_bf16(pv[0], pv[1]);
        pk[qh][kf][1] = cvt_pk_bf16(pv[2], pv[3]);
      }
#pragma unroll
    for (int g = 0; g < 2; g++) {
      union { bf8 v8; unsigned u[4]; } ap[2];
#pragma unroll
      for (int qh = 0; qh < 2; qh++) {
        ap[qh].u[0] = pk[qh][2 * g][0];
        ap[qh].u[1] = pk[qh][2 * g][1];
        ap[qh].u[2] = pk[qh][2 * g + 1][0];
        ap[qh].u[3] = pk[qh][2 * g + 1][1];
      }
#pragma unroll
      for (int nf2 = 0; nf2 < 4; nf2++) {
        int row = nf2 * 16 + l15;
        bf8 bv8 = *(const bf8*)(Vb + (size_t)row * 128 + (((4 * g + lhi) ^ (l15 & 7)) * 16));
#pragma unroll
        for (int qh = 0; qh < 2; qh++)
          o[qh][nf2] = mfma_bf16(ap[qh].v8, bv8, o[qh][nf2]);
      }
#pragma unroll
      for (int qh = 0; qh < 2; qh++)
        osum[qh] = mfma_bf16(ap[qh].v8, ones8, osum[qh]);   // row sums of P
    }
  };

  stage(0, 0);
  stage(1, 1);
  VWAIT(4);        // stage(0) complete; stage(1) may remain in flight
  BARRIER;

  f32x4 saccA[2][4], saccB[2][4];
  qk(0, saccA);    // tile 0

  int bc = 0;      // buffer holding current tile kt
  for (int kt2 = 0; kt2 < 8; kt2++) {
    {  // even tile kt = 2*kt2
      int kt = 2 * kt2;
      int bn = (bc == 2) ? 0 : bc + 1;
      int bs = (bn == 2) ? 0 : bn + 1;
      VWAIT(0);
      BARRIER;
      qk(bn, saccB);
      if (kt < 14) stage(kt + 2, bs);
      smpv(bc, saccA);
      bc = bn;
    }
    {  // odd tile kt = 2*kt2+1
      int kt = 2 * kt2 + 1;
      if (kt < 15) {
        int bn = (bc == 2) ? 0 : bc + 1;
        int bs = (bn == 2) ? 0 : bn + 1;
        VWAIT(0);
        BARRIER;
        qk(bn, saccA);
        if (kt < 14) stage(kt + 2, bs);
        smpv(bc, saccB);
        bc = bn;
      } else {
        smpv(bc, saccB);
      }
    }
  }

#pragma unroll
  for (int qh = 0; qh < 2; qh++) {
    float linv[4];
#pragma unroll
    for (int r = 0; r < 4; r++) linv[r] = 1.f / osum[qh][r];
#pragma unroll
    for (int nf2 = 0; nf2 < 4; nf2++)
#pragma unroll
      for (int r = 0; r < 4; r++) {
        float val = o[qh][nf2][r] * linv[r];
        ao[((size_t)b * NSP + q0 + qh * 16 + lhi * 4 + r) * CH_ + cb + nf2 * 16 + l15] = f2bf(val);
      }
  }
}

// ---------------- launch ----------------

extern "C" void kernel_launch(void* const* d_in, const int* in_sizes, int n_in,
                              void* d_out, int out_size, void* d_ws, size_t ws_size,
                              hipStream_t stream) {
  const float* x    = (const float*)d_in[0];
  const float* cnd  = (const float*)d_in[1];
  const float* c1w  = (const float*)d_in[2];
  const float* c1b  = (const float*)d_in[3];
  const float* g1w  = (const float*)d_in[4];
  const float* g1b  = (const float*)d_in[5];
  const float* c2w  = (const float*)d_in[6];
  const float* c2b  = (const float*)d_in[7];
  const float* g2w  = (const float*)d_in[8];
  const float* g2b  = (const float*)d_in[9];
  const float* cpw  = (const float*)d_in[10];
  const float* cpb  = (const float*)d_in[11];
  const float* rpw  = (const float*)d_in[12];
  const float* rpb  = (const float*)d_in[13];
  const float* qw   = (const float*)d_in[14];
  const float* qb   = (const float*)d_in[15];
  const float* kw   = (const float*)d_in[16];
  const float* kb   = (const float*)d_in[17];
  const float* vw   = (const float*)d_in[18];
  const float* vb   = (const float*)d_in[19];
  const float* ow   = (const float*)d_in[20];
  const float* ob   = (const float*)d_in[21];
  float* out = (float*)d_out;

  char* ws = (char*)d_ws;
  size_t off = 0;
  auto alloc = [&](size_t bytes) -> char* {
    char* p = ws + off;
    off = (off + bytes + 255) & ~(size_t)255;
    return p;
  };
  const size_t ACT_F = (size_t)NB * NSP * CH_ * 4;   // 16 MB
  const size_t ACT_B = (size_t)NB * NSP * CH_ * 2;   // 8 MB
  const size_t PAD_B = (size_t)NB * PPB * CH_ * 2;   // 9.47 MB

  u16* xp    = (u16*)alloc(PAD_B);               // x padded NHWC bf16
  u16* h1p   = (u16*)alloc(PAD_B);               // silu(gn1) padded bf16
  u16* w1p   = (u16*)alloc((size_t)9 * CH_ * CH_ * 2);
  u16* w2p   = (u16*)alloc((size_t)9 * CH_ * CH_ * 2);
  u16* wrp   = (u16*)alloc((size_t)CH_ * CH_ * 2);
  u16* wqkv  = (u16*)alloc((size_t)3 * CH_ * CH_ * 2);
  u16* wop   = (u16*)alloc((size_t)CH_ * CH_ * 2);
  float* cndv = (float*)alloc((size_t)NB * CH_ * 4);
  float* resid = (float*)alloc(ACT_F);           // residual f32 NHWC
  float* h12  = (float*)alloc(ACT_F);            // h f32 (gn2 out, addf input)
  u16* hb    = (u16*)alloc(ACT_B);               // h bf16 (attn input)
  u16* qbuf  = (u16*)alloc(ACT_B);               // Q (pre-scaled, exp2 domain) NHWC bf16
  u16* kbuf  = (u16*)alloc(ACT_B);               // K NHWC bf16
  u16* vTb   = (u16*)alloc(ACT_B);               // V^T [B][512][1024] bf16, kpos-permuted
  u16* aob   = (u16*)alloc(ACT_B);               // conv bf16 activations (actb); later attn out
  if (off > ws_size) return;

  u16* actb = aob;   // conv1/conv2 bf16 out, consumed by gn before attn reuses aob

  // merged prologue (pack_x + border_zero + pack_w3 x2 + pack_w1 x5 + cond)
  prep_kernel<<<8328, 256, 0, stream>>>(x, xp, h1p, c1w, c2w, w1p, w2p,
                                        rpw, qw, kw, vw, ow,
                                        wrp, wqkv, wqkv + (size_t)CH_ * CH_,
                                        wqkv + (size_t)2 * CH_ * CH_, wop,
                                        cnd, cpw, cpb, cndv);

  dim3 ggrid(NSP / 128, CH_ / 64, NB);
  dim3 qgrid(NSP / 128, 3 * CH_ / 64, NB);
  // conv1 (3x3, bf16 out) + FUSED residual proj -> actb bf16, resid f32
  conv_kernel<9, 1, 8><<<ggrid, 256, 0, stream>>>(xp, w1p, c1b, nullptr, nullptr,
                                                  actb, nullptr, nullptr, nullptr, nullptr, nullptr,
                                                  wrp, resid, rpb);
  // gn1 + silu -> h1p (padded bf16)
  gn_kernel<0><<<dim3(NGROUP, NB), 256, 0, stream>>>(actb, g1w, g1b, nullptr, nullptr, nullptr, h1p);
  // conv2 (3x3) -> actb bf16
  conv_kernel<9, 1, 7><<<ggrid, 256, 0, stream>>>(h1p, w2p, c2b, nullptr, nullptr,
                                                  actb, nullptr, nullptr, nullptr, nullptr, nullptr,
                                                  nullptr, nullptr, nullptr);
  // gn2 * (1+cond) + resid -> h12 f32, hb bf16
  gn_kernel<1><<<dim3(NGROUP, NB), 256, 0, stream>>>(actb, g2w, g2b, cndv, resid, h12, hb);
  // fused q/k/vT (1x1)
  conv_kernel<1, 0, 5><<<qgrid, 256, 0, stream>>>(hb, wqkv, nullptr, nullptr, nullptr,
                                                  qbuf, kbuf, vTb, qb, kb, vb,
                                                  nullptr, nullptr, nullptr);
  // attention -> aob bf16 NHWC (actb fully consumed by gn2 already)
  attn_kernel<<<512, 256, 0, stream>>>(qbuf, kbuf, vTb, aob);
  // out proj + bias + h -> d_out NCHW f32 directly
  conv_kernel<1, 0, 2><<<ggrid, 256, 0, stream>>>(aob, wop, ob, out, h12,
                                                  nullptr, nullptr, nullptr, nullptr, nullptr, nullptr,
                                                  nullptr, nullptr, nullptr);
}

// Round 16
// 220.877 us; speedup vs baseline: 1.0827x; 1.0007x over previous
//
#include <hip/hip_runtime.h>
#include <hip/hip_bf16.h>

typedef unsigned short u16;
typedef unsigned long long u64;
typedef __attribute__((ext_vector_type(8))) short bf8;   // 8 bf16 (raw bits, 4 VGPRs)
typedef __attribute__((ext_vector_type(4))) short bf4;   // 4 bf16 (2 VGPRs)
typedef __attribute__((ext_vector_type(4))) float f32x4;

#define CH_ 512
#define NSP 1024      // 32*32 spatial
#define NB 8
#define CONDDIM 1280
#define NGROUP 64     // 512/8
#define HEADS_ 8
#define HD 64         // head dim
#define PR 34         // padded row length (32 + 2)
#define PPB (PR*PR)   // padded positions per batch = 1156
#define QSCALE 0.18033688011112042f   // 0.125 * log2(e): softmax in exp2 domain

#define VWAIT(N) asm volatile("s_waitcnt vmcnt(" #N ")" ::: "memory")
#define SCHEDB __builtin_amdgcn_sched_barrier(0)
#define BARRIER do { SCHEDB; __builtin_amdgcn_s_barrier(); SCHEDB; } while (0)

__device__ __forceinline__ u16 f2bf(float f) {
  union { float f; unsigned u; } v; v.f = f;
  unsigned u = v.u;
  return (u16)((u + 0x7fffu + ((u >> 16) & 1u)) >> 16);   // RNE
}

__device__ __forceinline__ float b2f(u16 x) {
  union { unsigned u; float f; } v; v.u = ((unsigned)x) << 16; return v.f;
}

__device__ __forceinline__ unsigned cvt_pk_bf16(float lo, float hi) {
  unsigned r;
  asm volatile("v_cvt_pk_bf16_f32 %0, %1, %2" : "=v"(r) : "v"(lo), "v"(hi));
  return r;
}

__device__ __forceinline__ f32x4 mfma_bf16(bf8 a, bf8 b, f32x4 c) {
  return __builtin_amdgcn_mfma_f32_16x16x32_bf16(a, b, c, 0, 0, 0);
}

__device__ __forceinline__ void gload16(const void* g, void* l) {
  __builtin_amdgcn_global_load_lds((const __attribute__((address_space(1))) void*)g,
                                   (__attribute__((address_space(3))) void*)l, 16, 0, 0);
}

// ---------------- merged prologue kernel ----------------
// blockIdx ranges (256 threads each):
//   [0,4096)      pack_x: NCHW f32 -> padded NHWC bf16 (interior)
//   [4096,4360)   border zero xp & h1p         (264*256 == 8*132*64 exactly)
//   [4360,6664)   pack both 3x3 weights        (2*1152*256 == 2*9*64*512)
//   [6664,7304)   pack five 1x1 weights        (5*128*256 == 5*64*512)
//   [7304,8328)   cond GEMV                    (8*128 blocks)
__global__ __launch_bounds__(256) void prep_kernel(
    const float* __restrict__ x, u16* __restrict__ xp, u16* __restrict__ h1p,
    const float* __restrict__ c1w, const float* __restrict__ c2w,
    u16* __restrict__ w1p, u16* __restrict__ w2p,
    const float* __restrict__ rpw, const float* __restrict__ qw, const float* __restrict__ kw,
    const float* __restrict__ vw, const float* __restrict__ ow,
    u16* __restrict__ wrp, u16* __restrict__ wq, u16* __restrict__ wk,
    u16* __restrict__ wv, u16* __restrict__ wo,
    const float* __restrict__ cd, const float* __restrict__ cpw,
    const float* __restrict__ cpb, float* __restrict__ cond) {
  __shared__ float t[32][33];
  int bid = blockIdx.x;
  int tid = threadIdx.x;
  if (bid < 4096) {
    int px = bid & 31, py = (bid >> 5) & 15, b = bid >> 9;
    int c0 = py * 32, p0 = px * 32;
    int tx = tid & 31, ty = tid >> 5;
#pragma unroll
    for (int i = 0; i < 4; i++) {
      int row = ty + i * 8;
      t[row][tx] = x[((size_t)b * CH_ + c0 + row) * NSP + p0 + tx];
    }
    __syncthreads();
#pragma unroll
    for (int i = 0; i < 4; i++) {
      int pr = ty + i * 8;
      int p = p0 + pr;
      int y = p >> 5, xc = p & 31;
      xp[((size_t)b * PPB + (size_t)(y + 1) * PR + xc + 1) * CH_ + c0 + tx] = f2bf(t[tx][pr]);
    }
  } else if (bid < 4360) {
    int id = (bid - 4096) * 256 + tid;      // < 67584 == NB*132*64 exactly
    int ch8 = id & 63;
    int rest = id >> 6;
    int bidx = rest % 132;
    int bb = rest / 132;
    int r, c;
    if (bidx < 34)       { r = 0;          c = bidx; }
    else if (bidx < 68)  { r = 33;         c = bidx - 34; }
    else if (bidx < 100) { r = bidx - 67;  c = 0; }
    else                 { r = bidx - 99;  c = 33; }
    size_t off = ((size_t)bb * PPB + (size_t)r * PR + c) * CH_ + ch8 * 8;
    const bf8 z = {0, 0, 0, 0, 0, 0, 0, 0};
    *(bf8*)(xp + off) = z;
    *(bf8*)(h1p + off) = z;
  } else if (bid < 6664) {
    int id2 = bid - 4360;
    int which = (id2 >= 1152) ? 1 : 0;
    int id = (id2 - which * 1152) * 256 + tid;   // < 294912 == 9*64*512 exactly
    const float* w = which ? c2w : c1w;
    u16* wp = which ? w2p : w1p;
    int co = id & (CH_ - 1);
    int cib = (id >> 9) & 63;
    int tt = id >> 15;
    int dy = tt / 3, dx = tt % 3;
    bf8 v;
#pragma unroll
    for (int j = 0; j < 8; j++) {
      int ci = cib * 8 + j;
      v[j] = (short)f2bf(w[(((size_t)co * CH_ + ci) * 3 + dy) * 3 + dx]);
    }
    *(bf8*)(wp + ((size_t)(tt * 64 + cib) * CH_ + co) * 8) = v;
  } else if (bid < 7304) {
    int id3 = bid - 6664;
    int which = id3 >> 7;                   // 0..4
    int id = (id3 & 127) * 256 + tid;       // < 32768 == 64*512 exactly
    const float* w; u16* wp;
    switch (which) {
      case 0: w = rpw; wp = wrp; break;
      case 1: w = qw;  wp = wq;  break;
      case 2: w = kw;  wp = wk;  break;
      case 3: w = vw;  wp = wv;  break;
      default: w = ow; wp = wo;  break;
    }
    int co = id & (CH_ - 1);
    int cib = id >> 9;
    bf8 v;
#pragma unroll
    for (int j = 0; j < 8; j++) v[j] = (short)f2bf(w[(size_t)co * CH_ + cib * 8 + j]);
    *(bf8*)(wp + ((size_t)cib * CH_ + co) * 8) = v;
  } else {
    int id4 = bid - 7304;
    int b = id4 >> 7;
    int c = (id4 & 127) * 4 + (tid >> 6);
    int lane = tid & 63;
    const float* wrow = cpw + (size_t)c * CONDDIM;
    const float* crow = cd + (size_t)b * CONDDIM;
    float s = 0.f;
    for (int i = lane; i < CONDDIM; i += 64) s += crow[i] * wrow[i];
#pragma unroll
    for (int m = 32; m > 0; m >>= 1) s += __shfl_xor(s, m, 64);
    if (lane == 0) cond[b * CH_ + c] = s + cpb[c];
  }
}

// ---------------- counted-vmcnt implicit-GEMM conv ----------------
// A-tile LDS chunk XOR swizzle (c' = lhi ^ ((row>>1)&3)), both-sides (rule #21).
// 3x3: 3 taps/phase; B = TWO 12KB halves staged ONE phase ahead (r9-validated
//   waits: T0 vmcnt(2), T1 vmcnt(1) (+R: 2), T2 vmcnt(1)). conv2 LDS 52KB -> 3 blk/CU.
// 1x1: THREE slots (A 24KB + B 12KB = 36KB -> 4 blk/CU), 2-phase-ahead, vmcnt(3).
// EPI: 2 = FINAL f32 NCHW vectorized (+bias+addf NHWC);
//      5 = QKV fused (seg: q bf16*QSCALE / k bf16 / vT bf16 KPOS-PERMUTED);
//      7 = bf16 NHWC out (+bias)                        [conv2]
//      8 = conv1: bf16 NHWC out + FUSED residual 1x1 (center tap, wp2/bias2 -> outf2 f32)
template <int TAPS, int PIN, int EPI>
__global__ __launch_bounds__(256, TAPS == 9 ? 3 : 4) void conv_kernel(
    const u16* __restrict__ in, const u16* __restrict__ wp, const float* __restrict__ bias,
    float* __restrict__ outf, const float* __restrict__ addf,
    u16* __restrict__ o0, u16* __restrict__ o1, u16* __restrict__ o2,
    const float* __restrict__ b0, const float* __restrict__ b1, const float* __restrict__ b2,
    const u16* __restrict__ wp2, float* __restrict__ outf2, const float* __restrict__ bias2) {
  constexpr int LDSZ = (TAPS == 9) ? (2 * 14336 + 2 * 12288 + (EPI == 8 ? 2 * 4096 : 0))
                                   : (3 * 8192 + 3 * 4096);
  __shared__ char lds[LDSZ];
  char* ldsA = lds;
  char* ldsB = lds + ((TAPS == 9) ? 2 * 14336 : 3 * 8192);
  char* ldsR = lds + 2 * 14336 + 2 * 12288;   // only used when EPI==8

  const int b = blockIdx.z;
  int seg = 0, coy = blockIdx.y;
  if constexpr (EPI == 5) { seg = coy >> 3; coy &= 7; }
  const int co0 = coy * 64;
  const int p0 = blockIdx.x * 128;
  const int tid = threadIdx.x;
  const int lane = tid & 63, wid = tid >> 6;
  const int wv = wid >> 1, wc = wid & 1;
  const int l15 = lane & 15, lhi = lane >> 4;

  // global bases
  const char* aSrc;
  if constexpr (TAPS == 9) {
    aSrc = (const char*)in + ((size_t)b * PPB + (size_t)blockIdx.x * 4 * PR) * 1024;
  } else if constexpr (PIN) {
    aSrc = (const char*)in + (size_t)b * PPB * 1024;
  } else {
    aSrc = (const char*)in + ((size_t)b * NSP + p0) * 1024;
  }
  const char* bSrc = (const char*)wp + (size_t)((EPI == 5) ? seg * 524288 : 0) + co0 * 16;
  const char* rSrc = (const char*)wp2 + co0 * 16;   // EPI==8 only

  // per-thread staging source offsets (chunk pre-swizzled: c_src = (tid&3) ^ ((row>>1)&3))
  const int pB = ((tid >> 6) * 512 + (tid & 63)) * 16;
  int pA0, pA1, pA3 = 0;
  if constexpr (TAPS == 9) {
    int r0 = tid >> 2;
    int c0s = (tid & 3) ^ ((r0 >> 1) & 3);
    pA0 = (r0 << 10) + (c0s << 4);
    int r3 = 192 + ((tid & 127) >> 2);
    int c3s = (tid & 3) ^ ((r3 >> 1) & 3);
    pA3 = (r3 << 10) + (c3s << 4);
    pA1 = 0;
  } else {
    int a0 = (tid >> 2), a1 = 64 + (tid >> 2);
    int cs = (tid & 3) ^ (((tid >> 2) >> 1) & 3);
    if constexpr (PIN) {
      int pp0 = p0 + a0, pp1 = p0 + a1;
      int g0 = ((pp0 >> 5) + 1) * PR + (pp0 & 31) + 1;
      int g1 = ((pp1 >> 5) + 1) * PR + (pp1 & 31) + 1;
      pA0 = (g0 << 10) + (cs << 4);
      pA1 = (g1 << 10) + (cs << 4);
    } else {
      pA0 = (a0 << 10) + (cs << 4);
      pA1 = (a1 << 10) + (cs << 4);
    }
  }

  // per-thread LDS read bases
  const int rowbA = (TAPS == 9) ? (wv * 68 + l15) : (wv * 64 + l15);
  const int aAddr = rowbA * 64 + ((lhi ^ ((l15 >> 1) & 3)) << 4);      // 1x1 path only
  const int bAddr = (lhi * 64 + wc * 32 + l15) * 16;

  f32x4 acc[4][2], accR[4][2];
#pragma unroll
  for (int m = 0; m < 4; m++)
#pragma unroll
    for (int n = 0; n < 2; n++) { acc[m][n] = {0.f, 0.f, 0.f, 0.f}; accR[m][n] = {0.f, 0.f, 0.f, 0.f}; }

  if constexpr (TAPS == 9) {
    // ---- prologue: A(kc0) fully + B taps 0-2 (kc0) -> half 0 [+ R(kc0)] ----
    gload16(aSrc + pA0,          ldsA + (wid << 10));
    gload16(aSrc + pA0 + 65536,  ldsA + 4096 + (wid << 10));
    gload16(aSrc + pA0 + 131072, ldsA + 8192 + (wid << 10));
    gload16(aSrc + pA3,          ldsA + 12288 + ((wid & 1) << 10));
    gload16(bSrc + (size_t)(0 * 64) * 8192 + pB, ldsB + (wid << 10));
    gload16(bSrc + (size_t)(1 * 64) * 8192 + pB, ldsB + 4096 + (wid << 10));
    gload16(bSrc + (size_t)(2 * 64) * 8192 + pB, ldsB + 8192 + (wid << 10));
    if constexpr (EPI == 8) gload16(rSrc + pB, ldsR + (wid << 10));
    VWAIT(0);
    BARRIER;

// swizzled A fragment read: row = rowbA + K (K compile-time per fragment)
#define AREAD(Ab_, K) (*(const bf8*)((Ab_) + (rowbA + (K)) * 64 + ((lhi ^ (((rowbA + (K)) >> 1) & 3)) << 4)))

// phase (KC, T): consumes B half H, A buf AS; stages NEXT phase's 3 B tiles
// into half 1-H; A(kc+1) spread T0(2)/T1(1)/T2(1); R(kc+1) at T1.
#define PH3(KC, T, AS, H) do {                                                          \
    const int kcn_ = ((KC) < 15) ? (KC) + 1 : 15;                                       \
    { const int kb_ = ((T) == 2) ? kcn_ : (KC);                                         \
      const int tn_ = 3 * (((T) + 1) % 3);                                              \
      gload16(bSrc + (size_t)((tn_ + 0) * 64 + kb_ * 4) * 8192 + pB,                    \
              ldsB + (1 - (H)) * 12288 + (wid << 10));                                  \
      gload16(bSrc + (size_t)((tn_ + 1) * 64 + kb_ * 4) * 8192 + pB,                    \
              ldsB + (1 - (H)) * 12288 + 4096 + (wid << 10));                           \
      gload16(bSrc + (size_t)((tn_ + 2) * 64 + kb_ * 4) * 8192 + pB,                    \
              ldsB + (1 - (H)) * 12288 + 8192 + (wid << 10)); }                         \
    if constexpr ((T) == 0) {                                                           \
      gload16(aSrc + kcn_ * 64 + pA0,         ldsA + (1 - (AS)) * 14336 + (wid << 10)); \
      gload16(aSrc + kcn_ * 64 + pA0 + 65536, ldsA + (1 - (AS)) * 14336 + 4096 + (wid << 10)); \
    } else if constexpr ((T) == 1) {                                                    \
      gload16(aSrc + kcn_ * 64 + pA0 + 131072, ldsA + (1 - (AS)) * 14336 + 8192 + (wid << 10)); \
      if constexpr (EPI == 8)                                                           \
        if ((KC) < 15)                                                                  \
          gload16(rSrc + (size_t)kcn_ * 32768 + pB, ldsR + (kcn_ & 1) * 4096 + (wid << 10)); \
    } else {                                                                            \
      gload16(aSrc + kcn_ * 64 + pA3, ldsA + (1 - (AS)) * 14336 + 12288 + ((wid & 1) << 10)); \
    }                                                                                   \
    SCHEDB;                                                                             \
    {                                                                                   \
      const char* Ab_ = ldsA + (AS) * 14336;                                            \
      const char* Bb_ = ldsB + (H) * 12288;                                             \
      bf8 af_[3][4], bq_[3][2];                                                         \
      _Pragma("unroll")                                                                 \
      for (int tt = 0; tt < 3; tt++) {                                                  \
        const int DT_ = (T) * 34 + tt;                                                  \
        af_[tt][0] = AREAD(Ab_, DT_ + 0);                                               \
        af_[tt][1] = AREAD(Ab_, DT_ + 16);                                              \
        af_[tt][2] = AREAD(Ab_, DT_ + 34);                                              \
        af_[tt][3] = AREAD(Ab_, DT_ + 50);                                              \
        bq_[tt][0] = *(const bf8*)(Bb_ + tt * 4096 + 0   + bAddr);                      \
        bq_[tt][1] = *(const bf8*)(Bb_ + tt * 4096 + 256 + bAddr);                      \
      }                                                                                 \
      __builtin_amdgcn_s_setprio(1);                                                    \
      _Pragma("unroll")                                                                 \
      for (int tt = 0; tt < 3; tt++)                                                    \
        _Pragma("unroll")                                                               \
        for (int m = 0; m < 4; m++) {                                                   \
          acc[m][0] = mfma_bf16(af_[tt][m], bq_[tt][0], acc[m][0]);                     \
          acc[m][1] = mfma_bf16(af_[tt][m], bq_[tt][1], acc[m][1]);                     \
        }                                                                               \
      if constexpr (EPI == 8 && (T) == 1) {                                             \
        bf8 rq0 = *(const bf8*)(ldsR + ((KC) & 1) * 4096 + 0   + bAddr);                \
        bf8 rq1 = *(const bf8*)(ldsR + ((KC) & 1) * 4096 + 256 + bAddr);                \
        _Pragma("unroll")                                                               \
        for (int m = 0; m < 4; m++) {                                                   \
          accR[m][0] = mfma_bf16(af_[1][m], rq0, accR[m][0]);                           \
          accR[m][1] = mfma_bf16(af_[1][m], rq1, accR[m][1]);                           \
        }                                                                               \
      }                                                                                 \
      __builtin_amdgcn_s_setprio(0);                                                    \
    }                                                                                   \
    if constexpr ((T) == 0) { VWAIT(2); }                                               \
    else if constexpr ((T) == 1) {                                                      \
      if constexpr (EPI == 8) { VWAIT(2); } else { VWAIT(1); }                          \
    } else { VWAIT(1); }                                                                \
    BARRIER;                                                                            \
  } while (0)

    for (int kc2 = 0; kc2 < 8; kc2++) {
      PH3(kc2 * 2,     0, 0, 0); PH3(kc2 * 2,     1, 0, 1); PH3(kc2 * 2,     2, 0, 0);
      PH3(kc2 * 2 + 1, 0, 1, 1); PH3(kc2 * 2 + 1, 1, 1, 0); PH3(kc2 * 2 + 1, 2, 1, 1);
    }
#undef PH3
#undef AREAD
  } else {
    // ---- prologue: A(0),B(0) -> slot0; A(1),B(1) -> slot1 ----
    gload16(aSrc + pA0,         ldsA + (wid << 10));
    gload16(aSrc + pA1,         ldsA + 4096 + (wid << 10));
    gload16(bSrc + pB,          ldsB + (wid << 10));
    gload16(aSrc + 64 + pA0,    ldsA + 8192 + (wid << 10));
    gload16(aSrc + 64 + pA1,    ldsA + 8192 + 4096 + (wid << 10));
    gload16(bSrc + 32768 + pB,  ldsB + 4096 + (wid << 10));
    VWAIT(3);
    BARRIER;

// 3-slot rotation: phase KC consumes slot S=KC%3, stages KC+2 into (S+2)%3.
#define PH1(KC, S) do {                                                                 \
    constexpr int S2 = ((S) + 2) % 3;                                                   \
    const int kcn_ = ((KC) + 2 < 16) ? (KC) + 2 : 15;                                   \
    gload16(bSrc + (size_t)kcn_ * 32768 + pB, ldsB + S2 * 4096 + (wid << 10));          \
    gload16(aSrc + kcn_ * 64 + pA0, ldsA + S2 * 8192 + (wid << 10));                    \
    gload16(aSrc + kcn_ * 64 + pA1, ldsA + S2 * 8192 + 4096 + (wid << 10));             \
    SCHEDB;                                                                             \
    bf8 af0 = *(const bf8*)(ldsA + (S) * 8192 + 0    + aAddr);                          \
    bf8 af1 = *(const bf8*)(ldsA + (S) * 8192 + 1024 + aAddr);                          \
    bf8 af2 = *(const bf8*)(ldsA + (S) * 8192 + 2048 + aAddr);                          \
    bf8 af3 = *(const bf8*)(ldsA + (S) * 8192 + 3072 + aAddr);                          \
    bf8 bq0 = *(const bf8*)(ldsB + (S) * 4096 + 0   + bAddr);                           \
    bf8 bq1 = *(const bf8*)(ldsB + (S) * 4096 + 256 + bAddr);                           \
    __builtin_amdgcn_s_setprio(1);                                                      \
    acc[0][0] = mfma_bf16(af0, bq0, acc[0][0]);                                         \
    acc[0][1] = mfma_bf16(af0, bq1, acc[0][1]);                                         \
    acc[1][0] = mfma_bf16(af1, bq0, acc[1][0]);                                         \
    acc[1][1] = mfma_bf16(af1, bq1, acc[1][1]);                                         \
    acc[2][0] = mfma_bf16(af2, bq0, acc[2][0]);                                         \
    acc[2][1] = mfma_bf16(af2, bq1, acc[2][1]);                                         \
    acc[3][0] = mfma_bf16(af3, bq0, acc[3][0]);                                         \
    acc[3][1] = mfma_bf16(af3, bq1, acc[3][1]);                                         \
    __builtin_amdgcn_s_setprio(0);                                                      \
    VWAIT(3);                                                                           \
    BARRIER;                                                                            \
  } while (0)

    PH1(0, 0);  PH1(1, 1);  PH1(2, 2);  PH1(3, 0);
    PH1(4, 1);  PH1(5, 2);  PH1(6, 0);  PH1(7, 1);
    PH1(8, 2);  PH1(9, 0);  PH1(10, 1); PH1(11, 2);
    PH1(12, 0); PH1(13, 1); PH1(14, 2); PH1(15, 0);
#undef PH1
  }

  VWAIT(0);   // drain stray prefetches before LDS teardown

  // ---- epilogue ----
#pragma unroll
  for (int m = 0; m < 4; m++) {
    int pbase = p0 + wv * 64 + m * 16 + lhi * 4;
#pragma unroll
    for (int n = 0; n < 2; n++) {
      int co = co0 + wc * 32 + n * 16 + l15;
      if constexpr (EPI == 7) {
        float bv = bias[co];
#pragma unroll
        for (int r = 0; r < 4; r++)
          o0[((size_t)b * NSP + pbase + r) * CH_ + co] = f2bf(acc[m][n][r] + bv);
      } else if constexpr (EPI == 8) {
        float bv = bias[co];
        float rv = bias2[co];
#pragma unroll
        for (int r = 0; r < 4; r++) {
          size_t idx = ((size_t)b * NSP + pbase + r) * CH_ + co;
          o0[idx]    = f2bf(acc[m][n][r] + bv);
          outf2[idx] = accR[m][n][r] + rv;
        }
      } else if constexpr (EPI == 2) {
        float bv = bias[co];
        f32x4 v;
#pragma unroll
        for (int r = 0; r < 4; r++)
          v[r] = acc[m][n][r] + bv + addf[((size_t)b * NSP + pbase + r) * CH_ + co];
        *(f32x4*)(outf + ((size_t)b * CH_ + co) * NSP + pbase) = v;
      } else {  // EPI == 5 (qkv)
        if (seg == 0) {
          float bv = b0[co];
#pragma unroll
          for (int r = 0; r < 4; r++)
            o0[((size_t)b * NSP + pbase + r) * CH_ + co] = f2bf((acc[m][n][r] + bv) * QSCALE);
        } else if (seg == 1) {
          float bv = b1[co];
#pragma unroll
          for (int r = 0; r < 4; r++)
            o1[((size_t)b * NSP + pbase + r) * CH_ + co] = f2bf(acc[m][n][r] + bv);
        } else {
          float bv = b2[co];
          union { bf4 v; u64 u; } pk4;
#pragma unroll
          for (int r = 0; r < 4; r++) pk4.v[r] = (short)f2bf(acc[m][n][r] + bv);
          int np = (pbase & ~31) | ((pbase & 12) << 1) | ((pbase & 16) >> 2);  // kpos permute
          *(u64*)(o2 + ((size_t)b * CH_ + co) * NSP + np) = pk4.u;
        }
      }
    }
  }
}

// ---------------- GroupNorm (bf16 input, vectorized) ----------------
// MODE 0: y = silu(gn(x))              -> outb (bf16, PADDED NHWC)
// MODE 1: y = gn(x)*(1+cond)+resid     -> outf (f32) + outb (bf16 NHWC)
template <int MODE>
__global__ __launch_bounds__(256) void gn_kernel(
    const u16* __restrict__ in, const float* __restrict__ gw, const float* __restrict__ gb,
    const float* __restrict__ cond, const float* __restrict__ resid,
    float* __restrict__ outf, u16* __restrict__ outb) {
  int b = blockIdx.y, g = blockIdx.x;
  int tid = threadIdx.x;
  const u16* base = in + (size_t)b * NSP * CH_ + g * 8;
  bf8 v[4];
  float s = 0.f, ss = 0.f;
#pragma unroll
  for (int i = 0; i < 4; i++) {
    int p = tid + i * 256;
    v[i] = *(const bf8*)(base + (size_t)p * CH_);
#pragma unroll
    for (int j = 0; j < 8; j++) { float f = b2f((u16)v[i][j]); s += f; ss += f * f; }
  }
  __shared__ float rs[256], rss[256];
  rs[tid] = s; rss[tid] = ss;
  __syncthreads();
  for (int off = 128; off > 0; off >>= 1) {
    if (tid < off) { rs[tid] += rs[tid + off]; rss[tid] += rss[tid + off]; }
    __syncthreads();
  }
  float mean = rs[0] * (1.f / 8192.f);
  float var = rss[0] * (1.f / 8192.f) - mean * mean;
  float inv = rsqrtf(var + 1e-5f);
  float gam[8], bet[8], cm[8];
  *(f32x4*)(gam)     = *(const f32x4*)(gw + g * 8);
  *(f32x4*)(gam + 4) = *(const f32x4*)(gw + g * 8 + 4);
  *(f32x4*)(bet)     = *(const f32x4*)(gb + g * 8);
  *(f32x4*)(bet + 4) = *(const f32x4*)(gb + g * 8 + 4);
  if (MODE == 1) {
    *(f32x4*)(cm)     = *(const f32x4*)(cond + b * CH_ + g * 8);
    *(f32x4*)(cm + 4) = *(const f32x4*)(cond + b * CH_ + g * 8 + 4);
#pragma unroll
    for (int j = 0; j < 8; j++) cm[j] += 1.f;
  }
#pragma unroll
  for (int i = 0; i < 4; i++) {
    int p = tid + i * 256;
    if (MODE == 0) {
      bf8 ov;
#pragma unroll
      for (int j = 0; j < 8; j++) {
        float y = (b2f((u16)v[i][j]) - mean) * inv * gam[j] + bet[j];
        float sg = 1.f / (1.f + __expf(-y));
        ov[j] = (short)f2bf(y * sg);
      }
      int yy = p >> 5, xc = p & 31;
      *(bf8*)(outb + ((size_t)b * PPB + (size_t)(yy + 1) * PR + xc + 1) * CH_ + g * 8) = ov;
    } else {
      size_t idx = ((size_t)b * NSP + p) * CH_ + g * 8;
      f32x4 r0 = *(const f32x4*)(resid + idx);
      f32x4 r1 = *(const f32x4*)(resid + idx + 4);
      f32x4 z0, z1; bf8 ov;
#pragma unroll
      for (int j = 0; j < 4; j++) {
        float y = (b2f((u16)v[i][j]) - mean) * inv * gam[j] + bet[j];
        z0[j] = y * cm[j] + r0[j];
        ov[j] = (short)f2bf(z0[j]);
      }
#pragma unroll
      for (int j = 0; j < 4; j++) {
        float y = (b2f((u16)v[i][4 + j]) - mean) * inv * gam[4 + j] + bet[4 + j];
        z1[j] = y * cm[4 + j] + r1[j];
        ov[4 + j] = (short)f2bf(z1[j]);
      }
      *(f32x4*)(outf + idx)     = z0;
      *(f32x4*)(outf + idx + 4) = z1;
      *(bf8*)(outb + idx) = ov;
    }
  }
}

// ---------------- flash attention (2-tile pipeline, no-max exp2 softmax) ----------------
__global__ __launch_bounds__(256, 2) void attn_kernel(const u16* __restrict__ q, const u16* __restrict__ k,
                                                      const u16* __restrict__ vT, u16* __restrict__ ao) {
  int bid = blockIdx.x;
  int swz = (bid & 7) * 64 + (bid >> 3);   // XCD-bijective: each XCD owns one batch
  int b = swz >> 6;
  int head = (swz >> 3) & 7;
  int qt = swz & 7;
  int tid = threadIdx.x, lane = tid & 63, wid = tid >> 6;
  int l15 = lane & 15, lhi = lane >> 4;
  int cb = head * HD;
  int q0 = qt * 128 + wid * 32;

  const char* qp = (const char*)(q + (size_t)b * NSP * CH_ + cb);
  const char* kp = (const char*)(k + (size_t)b * NSP * CH_ + cb);
  const char* vp = (const char*)(vT + ((size_t)b * CH_ + cb) * NSP);

  __shared__ u16 Ksh[3][64 * 64];   // 24 KB
  __shared__ u16 Vsh[3][64 * 64];   // 24 KB

  bf8 aq[2][2];
#pragma unroll
  for (int qh = 0; qh < 2; qh++)
#pragma unroll
    for (int ks = 0; ks < 2; ks++)
      aq[qh][ks] = *(const bf8*)(qp + ((size_t)(q0 + qh * 16 + l15) * CH_ + ks * 32 + lhi * 8) * 2);

  const bf8 ones8 = {16256, 16256, 16256, 16256, 16256, 16256, 16256, 16256};  // bf16 1.0 x8

  f32x4 o[2][4], osum[2];
#pragma unroll
  for (int qh = 0; qh < 2; qh++) {
    osum[qh] = {0.f, 0.f, 0.f, 0.f};
#pragma unroll
    for (int n = 0; n < 4; n++) o[qh][n] = {0.f, 0.f, 0.f, 0.f};
  }

  auto stage = [&](int kt, int buf) {
#pragma unroll
    for (int t = 0; t < 2; t++) {
      int i = wid * 2 + t;
      int chunk = i * 64 + lane;             // 0..511
      int r = chunk >> 3, c = chunk & 7;
      gload16(kp + (size_t)(kt * 64 + r) * 1024 + (size_t)((c ^ (r & 7)) * 16),
              (char*)Ksh[buf] + i * 1024);
    }
#pragma unroll
    for (int t = 0; t < 2; t++) {
      int i = wid * 2 + t;
      int chunk = i * 64 + lane;
      int r = chunk >> 3, c = chunk & 7;     // r = d row of V^T
      gload16(vp + (size_t)r * 2048 + (size_t)(kt * 128) + (size_t)((c ^ (r & 7)) * 16),
              (char*)Vsh[buf] + i * 1024);
    }
  };

  auto qk = [&](int buf, f32x4 (&sacc)[2][4]) {
    const char* Kb = (const char*)Ksh[0] + buf * 8192;
#pragma unroll
    for (int qh = 0; qh < 2; qh++)
#pragma unroll
      for (int kf = 0; kf < 4; kf++) sacc[qh][kf] = {0.f, 0.f, 0.f, 0.f};
#pragma unroll
    for (int kf = 0; kf < 4; kf++) {
      bf8 ak[2];
#pragma unroll
      for (int ks = 0; ks < 2; ks++)
        ak[ks] = *(const bf8*)(Kb + (size_t)(kf * 16 + l15) * 128 + (((ks * 4 + lhi) ^ (l15 & 7)) * 16));
#pragma unroll
      for (int qh = 0; qh < 2; qh++)
#pragma unroll
        for (int ks = 0; ks < 2; ks++)
          sacc[qh][kf] = mfma_bf16(ak[ks], aq[qh][ks], sacc[qh][kf]);
    }
  };

  auto smpv = [&](int buf, f32x4 (&sacc)[2][4]) {
    const char* Vb = (const char*)Vsh[0] + buf * 8192;
    unsigned pk[2][4][2];
#pragma unroll
    for (int qh = 0; qh < 2; qh++)
#pragma unroll
      for (int kf = 0; kf < 4; kf++) {
        f32x4 pv;
#pragma unroll
        for (int r = 0; r < 4; r++) pv[r] = exp2f(sacc[qh][kf][r]);
        pk[qh][kf][0] = cvt_pk_bf16(pv[0], pv[1]);
        pk[qh][kf][1] = cvt_pk_bf16(pv[2], pv[3]);
      }
#pragma unroll
    for (int g = 0; g < 2; g++) {
      union { bf8 v8; unsigned u[4]; } ap[2];
#pragma unroll
      for (int qh = 0; qh < 2; qh++) {
        ap[qh].u[0] = pk[qh][2 * g][0];
        ap[qh].u[1] = pk[qh][2 * g][1];
        ap[qh].u[2] = pk[qh][2 * g + 1][0];
        ap[qh].u[3] = pk[qh][2 * g + 1][1];
      }
#pragma unroll
      for (int nf2 = 0; nf2 < 4; nf2++) {
        int row = nf2 * 16 + l15;
        bf8 bv8 = *(const bf8*)(Vb + (size_t)row * 128 + (((4 * g + lhi) ^ (l15 & 7)) * 16));
#pragma unroll
        for (int qh = 0; qh < 2; qh++)
          o[qh][nf2] = mfma_bf16(ap[qh].v8, bv8, o[qh][nf2]);
      }
#pragma unroll
      for (int qh = 0; qh < 2; qh++)
        osum[qh] = mfma_bf16(ap[qh].v8, ones8, osum[qh]);   // row sums of P
    }
  };

  stage(0, 0);
  stage(1, 1);
  VWAIT(4);        // stage(0) complete; stage(1) may remain in flight
  BARRIER;

  f32x4 saccA[2][4], saccB[2][4];
  qk(0, saccA);    // tile 0

  int bc = 0;      // buffer holding current tile kt
  for (int kt2 = 0; kt2 < 8; kt2++) {
    {  // even tile kt = 2*kt2
      int kt = 2 * kt2;
      int bn = (bc == 2) ? 0 : bc + 1;
      int bs = (bn == 2) ? 0 : bn + 1;
      VWAIT(0);
      BARRIER;
      qk(bn, saccB);
      if (kt < 14) stage(kt + 2, bs);
      smpv(bc, saccA);
      bc = bn;
    }
    {  // odd tile kt = 2*kt2+1
      int kt = 2 * kt2 + 1;
      if (kt < 15) {
        int bn = (bc == 2) ? 0 : bc + 1;
        int bs = (bn == 2) ? 0 : bn + 1;
        VWAIT(0);
        BARRIER;
        qk(bn, saccA);
        if (kt < 14) stage(kt + 2, bs);
        smpv(bc, saccB);
        bc = bn;
      } else {
        smpv(bc, saccB);
      }
    }
  }

#pragma unroll
  for (int qh = 0; qh < 2; qh++) {
    float linv[4];
#pragma unroll
    for (int r = 0; r < 4; r++) linv[r] = 1.f / osum[qh][r];
#pragma unroll
    for (int nf2 = 0; nf2 < 4; nf2++)
#pragma unroll
      for (int r = 0; r < 4; r++) {
        float val = o[qh][nf2][r] * linv[r];
        ao[((size_t)b * NSP + q0 + qh * 16 + lhi * 4 + r) * CH_ + cb + nf2 * 16 + l15] = f2bf(val);
      }
  }
}

// ---------------- launch ----------------

extern "C" void kernel_launch(void* const* d_in, const int* in_sizes, int n_in,
                              void* d_out, int out_size, void* d_ws, size_t ws_size,
                              hipStream_t stream) {
  const float* x    = (const float*)d_in[0];
  const float* cnd  = (const float*)d_in[1];
  const float* c1w  = (const float*)d_in[2];
  const float* c1b  = (const float*)d_in[3];
  const float* g1w  = (const float*)d_in[4];
  const float* g1b  = (const float*)d_in[5];
  const float* c2w  = (const float*)d_in[6];
  const float* c2b  = (const float*)d_in[7];
  const float* g2w  = (const float*)d_in[8];
  const float* g2b  = (const float*)d_in[9];
  const float* cpw  = (const float*)d_in[10];
  const float* cpb  = (const float*)d_in[11];
  const float* rpw  = (const float*)d_in[12];
  const float* rpb  = (const float*)d_in[13];
  const float* qw   = (const float*)d_in[14];
  const float* qb   = (const float*)d_in[15];
  const float* kw   = (const float*)d_in[16];
  const float* kb   = (const float*)d_in[17];
  const float* vw   = (const float*)d_in[18];
  const float* vb   = (const float*)d_in[19];
  const float* ow   = (const float*)d_in[20];
  const float* ob   = (const float*)d_in[21];
  float* out = (float*)d_out;

  char* ws = (char*)d_ws;
  size_t off = 0;
  auto alloc = [&](size_t bytes) -> char* {
    char* p = ws + off;
    off = (off + bytes + 255) & ~(size_t)255;
    return p;
  };
  const size_t ACT_F = (size_t)NB * NSP * CH_ * 4;   // 16 MB
  const size_t ACT_B = (size_t)NB * NSP * CH_ * 2;   // 8 MB
  const size_t PAD_B = (size_t)NB * PPB * CH_ * 2;   // 9.47 MB

  u16* xp    = (u16*)alloc(PAD_B);               // x padded NHWC bf16
  u16* h1p   = (u16*)alloc(PAD_B);               // silu(gn1) padded bf16
  u16* w1p   = (u16*)alloc((size_t)9 * CH_ * CH_ * 2);
  u16* w2p   = (u16*)alloc((size_t)9 * CH_ * CH_ * 2);
  u16* wrp   = (u16*)alloc((size_t)CH_ * CH_ * 2);
  u16* wqkv  = (u16*)alloc((size_t)3 * CH_ * CH_ * 2);
  u16* wop   = (u16*)alloc((size_t)CH_ * CH_ * 2);
  float* cndv = (float*)alloc((size_t)NB * CH_ * 4);
  float* resid = (float*)alloc(ACT_F);           // residual f32 NHWC
  float* h12  = (float*)alloc(ACT_F);            // h f32 (gn2 out, addf input)
  u16* hb    = (u16*)alloc(ACT_B);               // h bf16 (attn input)
  u16* qbuf  = (u16*)alloc(ACT_B);               // Q (pre-scaled, exp2 domain) NHWC bf16
  u16* kbuf  = (u16*)alloc(ACT_B);               // K NHWC bf16
  u16* vTb   = (u16*)alloc(ACT_B);               // V^T [B][512][1024] bf16, kpos-permuted
  u16* aob   = (u16*)alloc(ACT_B);               // conv bf16 activations (actb); later attn out
  if (off > ws_size) return;

  u16* actb = aob;   // conv1/conv2 bf16 out, consumed by gn before attn reuses aob

  // merged prologue (pack_x + border_zero + pack_w3 x2 + pack_w1 x5 + cond)
  prep_kernel<<<8328, 256, 0, stream>>>(x, xp, h1p, c1w, c2w, w1p, w2p,
                                        rpw, qw, kw, vw, ow,
                                        wrp, wqkv, wqkv + (size_t)CH_ * CH_,
                                        wqkv + (size_t)2 * CH_ * CH_, wop,
                                        cnd, cpw, cpb, cndv);

  dim3 ggrid(NSP / 128, CH_ / 64, NB);
  dim3 qgrid(NSP / 128, 3 * CH_ / 64, NB);
  // conv1 (3x3, bf16 out) + FUSED residual proj -> actb bf16, resid f32
  conv_kernel<9, 1, 8><<<ggrid, 256, 0, stream>>>(xp, w1p, c1b, nullptr, nullptr,
                                                  actb, nullptr, nullptr, nullptr, nullptr, nullptr,
                                                  wrp, resid, rpb);
  // gn1 + silu -> h1p (padded bf16)
  gn_kernel<0><<<dim3(NGROUP, NB), 256, 0, stream>>>(actb, g1w, g1b, nullptr, nullptr, nullptr, h1p);
  // conv2 (3x3) -> actb bf16
  conv_kernel<9, 1, 7><<<ggrid, 256, 0, stream>>>(h1p, w2p, c2b, nullptr, nullptr,
                                                  actb, nullptr, nullptr, nullptr, nullptr, nullptr,
                                                  nullptr, nullptr, nullptr);
  // gn2 * (1+cond) + resid -> h12 f32, hb bf16
  gn_kernel<1><<<dim3(NGROUP, NB), 256, 0, stream>>>(actb, g2w, g2b, cndv, resid, h12, hb);
  // fused q/k/vT (1x1)
  conv_kernel<1, 0, 5><<<qgrid, 256, 0, stream>>>(hb, wqkv, nullptr, nullptr, nullptr,
                                                  qbuf, kbuf, vTb, qb, kb, vb,
                                                  nullptr, nullptr, nullptr);
  // attention -> aob bf16 NHWC (actb fully consumed by gn2 already)
  attn_kernel<<<512, 256, 0, stream>>>(qbuf, kbuf, vTb, aob);
  // out proj + bias + h -> d_out NCHW f32 directly
  conv_kernel<1, 0, 2><<<ggrid, 256, 0, stream>>>(aob, wop, ob, out, h12,
                                                  nullptr, nullptr, nullptr, nullptr, nullptr, nullptr,
                                                  nullptr, nullptr, nullptr);
}